// Round 5
// baseline (313.295 us; speedup 1.0000x reference)
//
#include <hip/hip_runtime.h>

#define TPB 256

// Problem dims
constexpr int B_ = 4096, A_ = 11;
constexpr int R_ = B_ * A_;       // 45056 rows

// ws offsets (floats). MH2/BH2 alias regions dead after preC.
constexpr int M_O     = 0;        // 8192   folded through fc2 (32x256)
constexpr int M2_O    = 8192;     // 8192   folded through fc3 (32x256)
constexpr int WC_O    = 16384;    // 1024   W_in @ W_pos_top       [dead after preC]
constexpr int XB_O    = 19712;    // 2048   per-timestep bias      [dead after preC]
constexpr int CB_O    = 21760;    // 256
constexpr int B2_O    = 22016;    // 2816   per-agent bias (11x256)
constexpr int WN2L_O  = 24832;    // 4096   Wn2 @ W_line (64x64)
constexpr int MH1_O   = 28928;    // 2048   M2 @ Wh1 (32x64)
constexpr int BH1_O   = 30976;    // 704
constexpr int MH2_O   = 16384;    // 2048   (aliases WC, dead by preE)
constexpr int BH2_O   = 18432;    // 704    (aliases dead region)

// ================= pre kernels: wide split-K folds (unchanged, passing) =================

__global__ __launch_bounds__(TPB) void k_preAB(const float* __restrict__ Win,
                                               const float* __restrict__ bin,
                                               const float* __restrict__ Wpos,
                                               const float* __restrict__ bpos,
                                               const float* __restrict__ Wn2,
                                               const float* __restrict__ Wline,
                                               float* __restrict__ ws) {
    __shared__ float red[8 * 33];
    const int t = threadIdx.x, o8 = t & 31, ks = t >> 5;
    const int bx = blockIdx.x;
    if (bx < 32) {                       // Wc[i][j], 1024 outs, K=256
        int o = bx * 32 + o8, i = o >> 8, j = o & 255;
        const float* Ar = Win + i * 256;
        float p = 0.f;
        #pragma unroll 8
        for (int d = ks * 32; d < ks * 32 + 32; ++d) p += Ar[d] * Wpos[d * 256 + j];
        red[ks * 33 + o8] = p;
        __syncthreads();
        if (t < 32) {
            float s = 0.f;
            #pragma unroll
            for (int m = 0; m < 8; ++m) s += red[m * 33 + t];
            ws[WC_O + bx * 32 + t] = s;
        }
    } else if (bx < 96) {                // xb[l][j], 2048 outs, K=512 (bin then pe inline)
        int o = (bx - 32) * 32 + o8, l = o >> 8, j = o & 255;
        const float c0 = -logf(10000.f) / 256.f;
        float p = 0.f;
        for (int d = ks * 64; d < ks * 64 + 64; ++d) {
            float a;
            if (d < 256) a = bin[d];
            else {
                int dd = d - 256;
                float freq = expf((float)(dd & ~1) * c0);
                float ang = (float)l * freq;
                a = (dd & 1) ? cosf(ang) : sinf(ang);
            }
            p += a * Wpos[d * 256 + j];
        }
        red[ks * 33 + o8] = p;
        __syncthreads();
        if (t < 32) {
            int oo = (bx - 32) * 32 + t;
            float s = bpos[oo & 255];
            #pragma unroll
            for (int m = 0; m < 8; ++m) s += red[m * 33 + t];
            ws[XB_O + oo] = s;
        }
    } else {                             // Wn2L = Wn2 @ W_line, 4096 outs, 128 blocks
        int o = (bx - 96) * 32 + o8, k = o >> 6, c = o & 63;
        const float* Ar = Wn2 + k * 256;
        float p = 0.f;
        #pragma unroll 8
        for (int d = ks * 32; d < ks * 32 + 32; ++d) p += Ar[d] * Wline[d * 64 + c];
        red[ks * 33 + o8] = p;
        __syncthreads();
        if (t < 32) {
            float s = 0.f;
            #pragma unroll
            for (int m = 0; m < 8; ++m) s += red[m * 33 + t];
            ws[WN2L_O + (bx - 96) * 32 + t] = s;
        }
    }
}

__global__ __launch_bounds__(TPB) void k_preC(const float* __restrict__ Wfc2,
                                              const float* __restrict__ bfc2,
                                              float* __restrict__ ws) {
    __shared__ float red[8 * 33];
    const int t = threadIdx.x, o8 = t & 31, ks = t >> 5;
    const int bx = blockIdx.x;
    if (bx < 256) {                      // M[k][j], 8192 outs, K=256; k=(l,i)
        int o = bx * 32 + o8, k = o >> 8, j = o & 255;
        int l = k >> 2, i = k & 3;
        const float* Ar = ws + WC_O + i * 256;
        const float* Br = Wfc2 + l * 65536 + j;
        float p = 0.f;
        #pragma unroll 8
        for (int d = ks * 32; d < ks * 32 + 32; ++d) p += Ar[d] * Br[d * 256];
        red[ks * 33 + o8] = p;
        __syncthreads();
        if (t < 32) {
            float s = 0.f;
            #pragma unroll
            for (int m = 0; m < 8; ++m) s += red[m * 33 + t];
            ws[M_O + bx * 32 + t] = s;
        }
    } else {                             // cb[j], 256 outs, K=2048
        int j = (bx - 256) * 32 + o8;
        const float* Ar = ws + XB_O;
        float p = 0.f;
        #pragma unroll 4
        for (int dk = ks * 256; dk < ks * 256 + 256; ++dk) p += Ar[dk] * Wfc2[dk * 256 + j];
        red[ks * 33 + o8] = p;
        __syncthreads();
        if (t < 32) {
            int jj = (bx - 256) * 32 + t;
            float s = bfc2[jj];
            #pragma unroll
            for (int m = 0; m < 8; ++m) s += red[m * 33 + t];
            ws[CB_O + jj] = s;
        }
    }
}

__global__ __launch_bounds__(TPB) void k_preD(const float* __restrict__ Wfc3,
                                              const float* __restrict__ bfc3,
                                              float* __restrict__ ws) {
    __shared__ float red[8 * 33];
    const int t = threadIdx.x, o8 = t & 31, ks = t >> 5;
    const int bx = blockIdx.x;
    if (bx < 256) {                      // M2 = M @ Wfc3_top, 8192 outs
        int o = bx * 32 + o8, k = o >> 8, j = o & 255;
        const float* Ar = ws + M_O + k * 256;
        float p = 0.f;
        #pragma unroll 8
        for (int d = ks * 32; d < ks * 32 + 32; ++d) p += Ar[d] * Wfc3[d * 256 + j];
        red[ks * 33 + o8] = p;
        __syncthreads();
        if (t < 32) {
            float s = 0.f;
            #pragma unroll
            for (int m = 0; m < 8; ++m) s += red[m * 33 + t];
            ws[M2_O + bx * 32 + t] = s;
        }
    } else {                             // bias2[a][j], 2816 outs (88 blocks)
        int o = (bx - 256) * 32 + o8, j = o & 255;
        const float* Ar = ws + CB_O;
        float p = 0.f;
        #pragma unroll 8
        for (int d = ks * 32; d < ks * 32 + 32; ++d) p += Ar[d] * Wfc3[d * 256 + j];
        red[ks * 33 + o8] = p;
        __syncthreads();
        if (t < 32) {
            int oo = (bx - 256) * 32 + t;
            int aa = oo >> 8, jj = oo & 255;
            float s = bfc3[jj] + Wfc3[(256 + aa) * 256 + jj];
            #pragma unroll
            for (int m = 0; m < 8; ++m) s += red[m * 33 + t];
            ws[B2_O + oo] = s;
        }
    }
}

__global__ __launch_bounds__(TPB) void k_preE(const float* __restrict__ Wh1,
                                              const float* __restrict__ Wh2,
                                              float* __restrict__ ws) {
    __shared__ float red[8 * 33];
    const int t = threadIdx.x, o8 = t & 31, ks = t >> 5;
    const int bx = blockIdx.x;
    const float* Bw;  int oo_base;  int out_o;  int mode;
    if (bx < 64)       { mode = 0; out_o = MH1_O; oo_base = bx * 32;         Bw = Wh1; }
    else if (bx < 86)  { mode = 1; out_o = BH1_O; oo_base = (bx - 64) * 32;  Bw = Wh1; }
    else if (bx < 150) { mode = 0; out_o = MH2_O; oo_base = (bx - 86) * 32;  Bw = Wh2; }
    else               { mode = 1; out_o = BH2_O; oo_base = (bx - 150) * 32; Bw = Wh2; }
    int o = oo_base + o8;
    int r = o >> 6, c = o & 63;
    const float* Aw = ws + (mode == 0 ? M2_O : B2_O) + r * 256;
    float p = 0.f;
    #pragma unroll 8
    for (int d = ks * 32; d < ks * 32 + 32; ++d) p += Aw[d] * Bw[d * 64 + c];
    red[ks * 33 + o8] = p;
    __syncthreads();
    if (t < 32) {
        float s = 0.f;
        #pragma unroll
        for (int m = 0; m < 8; ++m) s += red[m * 33 + t];
        ws[out_o + oo_base + t] = s;
    }
}

// ================= k_fused: wave-per-scene, everything in one kernel =================
// Block = 4 scenes (44 rows), wave w owns scene w. A-operands broadcast from LDS;
// u/v/agg entirely in registers; corr/threshold wave-local; no intermediate HBM.

__device__ __forceinline__ void fma4(float4& a, float s, const float4& b) {
    a.x += s * b.x; a.y += s * b.y; a.z += s * b.z; a.w += s * b.w;
}

__global__ __launch_bounds__(TPB, 4) void k_fused(const float* __restrict__ in,
                                                  const float* __restrict__ We1g,
                                                  const float* __restrict__ We2g,
                                                  const float* __restrict__ Wn1,
                                                  const float* __restrict__ ws,
                                                  float* __restrict__ out) {
    __shared__ float inS[44 * 36];     // 6.3 KB
    __shared__ float cS[44 * 68];      // 12 KB — ft-chunk / h / agg buffer
    __shared__ float Bs[2048];         // 8 KB  — Mh / We staging
    __shared__ float dotsS[4 * 121];
    __shared__ float corrS[4 * 121];
    const int t = threadIdx.x;
    const int w = t >> 6, lane = t & 63;
    const int rowBlk = blockIdx.x * 44;
    const int wr = w * 11;

    // stage input (44 rows x 32)
    for (int o = t; o < 352; o += TPB) {
        int row = o >> 3, c4 = o & 7;
        *(float4*)&inS[row * 36 + c4 * 4] =
            *(const float4*)&in[(size_t)(rowBlk + row) * 32 + c4 * 4];
    }

    // symmetric dot-pair assignment: q = lane (<66) and lane+64 (lanes 0,1)
    int pi0 = 0, pj0 = 0, pi1 = 0, pj1 = 0;
    const bool has0 = lane < 66;
    const bool has1 = lane < 2;
    {
        int q = has0 ? lane : 0, i = 0;
        while (q >= 11 - i) { q -= 11 - i; ++i; }
        pi0 = i; pj0 = i + q;
        if (has1) {
            int q2 = lane + 64, i2 = 0;
            while (q2 >= 11 - i2) { q2 -= 11 - i2; ++i2; }
            pi1 = i2; pj1 = i2 + q2;
        }
    }
    __syncthreads();

    // ---- ftraj = in @ M2 + bias2; cols lane*4; B streamed from L2 ----
    float4 ft[11];
    {
        const float* M2g = ws + M2_O;
        #pragma unroll
        for (int i = 0; i < 11; ++i) ft[i] = make_float4(0.f, 0.f, 0.f, 0.f);
        #pragma unroll
        for (int kq = 0; kq < 8; ++kq) {
            float4 b[4];
            #pragma unroll
            for (int kk = 0; kk < 4; ++kk)
                b[kk] = *(const float4*)&M2g[(kq * 4 + kk) * 256 + lane * 4];
            #pragma unroll
            for (int i = 0; i < 11; ++i) {
                float4 a4 = *(const float4*)&inS[(wr + i) * 36 + kq * 4];
                fma4(ft[i], a4.x, b[0]); fma4(ft[i], a4.y, b[1]);
                fma4(ft[i], a4.z, b[2]); fma4(ft[i], a4.w, b[3]);
            }
        }
        #pragma unroll
        for (int i = 0; i < 11; ++i) {
            float4 b2 = *(const float4*)&ws[B2_O + i * 256 + lane * 4];
            ft[i].x += b2.x; ft[i].y += b2.y; ft[i].z += b2.z; ft[i].w += b2.w;
            *(float4*)&out[(size_t)(rowBlk + wr + i) * 576 + lane * 4] = ft[i];
        }
    }

    // ---- dots over 4 col-chunks via cS (wave-private rows) ----
    float dacc0 = 0.f, dacc1 = 0.f;
    for (int ch = 0; ch < 4; ++ch) {
        __syncthreads();
        if ((lane >> 4) == ch) {
            int cl = (lane & 15) * 4;
            #pragma unroll
            for (int i = 0; i < 11; ++i)
                *(float4*)&cS[(wr + i) * 68 + cl] = ft[i];
        }
        __syncthreads();
        if (has0) {
            const float* ra = &cS[(wr + pi0) * 68];
            const float* rb = &cS[(wr + pj0) * 68];
            #pragma unroll
            for (int cc = 0; cc < 16; ++cc) {
                float4 a = *(const float4*)&ra[cc * 4];
                float4 b = *(const float4*)&rb[cc * 4];
                dacc0 += a.x * b.x + a.y * b.y + a.z * b.z + a.w * b.w;
            }
        }
        if (has1) {
            const float* ra = &cS[(wr + pi1) * 68];
            const float* rb = &cS[(wr + pj1) * 68];
            #pragma unroll
            for (int cc = 0; cc < 16; ++cc) {
                float4 a = *(const float4*)&ra[cc * 4];
                float4 b = *(const float4*)&rb[cc * 4];
                dacc1 += a.x * b.x + a.y * b.y + a.z * b.z + a.w * b.w;
            }
        }
    }
    if (has0) { dotsS[w * 121 + pi0 * 11 + pj0] = dacc0;
                dotsS[w * 121 + pj0 * 11 + pi0] = dacc0; }
    if (has1) { dotsS[w * 121 + pi1 * 11 + pj1] = dacc1;
                dotsS[w * 121 + pj1 * 11 + pi1] = dacc1; }
    __syncthreads();

    // ---- corr + scene threshold (wave-local) ----
    float thr;
    {
        const float* dw = &dotsS[w * 121];
        int q = lane, i = q / 11, j = q % 11;
        float c0 = dw[q] * rsqrtf(dw[i * 11 + i] * dw[j * 11 + j]);
        corrS[w * 121 + q] = c0;
        float mn = c0;
        int q2 = lane + 64;
        if (q2 < 121) {
            int i2 = q2 / 11, j2 = q2 % 11;
            float c1 = dw[q2] * rsqrtf(dw[i2 * 11 + i2] * dw[j2 * 11 + j2]);
            corrS[w * 121 + q2] = c1;
            mn = fminf(mn, c1);
        }
        #pragma unroll
        for (int off = 32; off; off >>= 1) mn = fminf(mn, __shfl_xor(mn, off));
        thr = (mn < 0.4f) ? 0.4f : ((mn > 0.4f && mn < 0.6f) ? mn + 0.1f : mn + 0.03f);
    }

    // ---- two NMP stages; u,v,agg in registers ----
    float agg1[11], agg2[11];
    for (int st = 0; st < 2; ++st) {
        const float* Weg = st ? We2g : We1g;
        const float* bhg = ws + (st ? BH2_O : BH1_O);
        __syncthreads();
        {   // stage Mh (32x64)
            const float4* src = (const float4*)(ws + (st ? MH2_O : MH1_O));
            ((float4*)Bs)[t] = src[t];
            ((float4*)Bs)[t + 256] = src[t + 256];
        }
        __syncthreads();
        float h[11];
        {
            #pragma unroll
            for (int i = 0; i < 11; ++i) h[i] = 0.f;
            #pragma unroll
            for (int kq = 0; kq < 8; ++kq) {
                float bq[4];
                #pragma unroll
                for (int kk = 0; kk < 4; ++kk) bq[kk] = Bs[(kq * 4 + kk) * 64 + lane];
                #pragma unroll
                for (int i = 0; i < 11; ++i) {
                    float4 a4 = *(const float4*)&inS[(wr + i) * 36 + kq * 4];
                    h[i] += a4.x * bq[0] + a4.y * bq[1] + a4.z * bq[2] + a4.w * bq[3];
                }
            }
            #pragma unroll
            for (int i = 0; i < 11; ++i)
                h[i] = fmaxf(h[i] + bhg[i * 64 + lane], 0.f);
        }
        __syncthreads();          // prior cS readers done (dots / st0 uv)
        #pragma unroll
        for (int i = 0; i < 11; ++i) cS[(wr + i) * 68 + lane] = h[i];

        float u[11], v[11];
        #pragma unroll
        for (int i = 0; i < 11; ++i) { u[i] = 0.f; v[i] = 0.f; }
        for (int kh = 0; kh < 4; ++kh) {
            __syncthreads();      // kh=0: h-writes done + h's Bs reads done; kh>0: Bs reads done
            {   // stage We rows [kh*16,+16) (u) and [64+kh*16,+16) (v)
                int k = t >> 4, c4 = t & 15;
                ((float4*)Bs)[t] = *(const float4*)&Weg[(kh * 16 + k) * 64 + c4 * 4];
                ((float4*)(Bs + 1024))[t] = *(const float4*)&Weg[(64 + kh * 16 + k) * 64 + c4 * 4];
            }
            __syncthreads();
            #pragma unroll
            for (int kq = 0; kq < 4; ++kq) {
                float bu[4], bv[4];
                #pragma unroll
                for (int kk = 0; kk < 4; ++kk) {
                    bu[kk] = Bs[(kq * 4 + kk) * 64 + lane];
                    bv[kk] = Bs[1024 + (kq * 4 + kk) * 64 + lane];
                }
                #pragma unroll
                for (int i = 0; i < 11; ++i) {
                    float4 a4 = *(const float4*)&cS[(wr + i) * 68 + kh * 16 + kq * 4];
                    u[i] += a4.x * bu[0] + a4.y * bu[1] + a4.z * bu[2] + a4.w * bu[3];
                    v[i] += a4.x * bv[0] + a4.y * bv[1] + a4.z * bv[2] + a4.w * bv[3];
                }
            }
        }
        if (st == 0) {
            #pragma unroll
            for (int i = 0; i < 11; ++i) {
                float s = 0.f;
                #pragma unroll
                for (int j = 0; j < 11; ++j) s += fmaxf(u[i] + v[j], 0.f);
                agg1[i] = s * (1.f / 11.f);
            }
        } else {
            #pragma unroll
            for (int i = 0; i < 11; ++i) {
                float s = 0.f, cnt = 0.f;
                #pragma unroll
                for (int j = 0; j < 11; ++j) {
                    float adj = (corrS[w * 121 + i * 11 + j] >= thr) ? 1.f : 0.f;
                    s += adj * fmaxf(u[i] + v[j], 0.f);
                    cnt += adj;
                }
                agg2[i] = s / (cnt + 1e-6f);
            }
        }
    }

    // ---- inter = agg1 @ Wn1 -> out[:,256:512]; B streamed from L2 ----
    __syncthreads();
    #pragma unroll
    for (int i = 0; i < 11; ++i) cS[(wr + i) * 68 + lane] = agg1[i];
    __syncthreads();
    {
        float4 acc[11];
        #pragma unroll
        for (int i = 0; i < 11; ++i) acc[i] = make_float4(0.f, 0.f, 0.f, 0.f);
        #pragma unroll 4
        for (int kq = 0; kq < 16; ++kq) {
            float4 b[4];
            #pragma unroll
            for (int kk = 0; kk < 4; ++kk)
                b[kk] = *(const float4*)&Wn1[(kq * 4 + kk) * 256 + lane * 4];
            #pragma unroll
            for (int i = 0; i < 11; ++i) {
                float4 a4 = *(const float4*)&cS[(wr + i) * 68 + kq * 4];
                fma4(acc[i], a4.x, b[0]); fma4(acc[i], a4.y, b[1]);
                fma4(acc[i], a4.z, b[2]); fma4(acc[i], a4.w, b[3]);
            }
        }
        #pragma unroll
        for (int i = 0; i < 11; ++i)
            *(float4*)&out[(size_t)(rowBlk + wr + i) * 576 + 256 + lane * 4] = acc[i];
    }

    // ---- feat = agg2 @ Wn2L -> out[:,512:576] ----
    __syncthreads();
    #pragma unroll
    for (int i = 0; i < 11; ++i) cS[(wr + i) * 68 + lane] = agg2[i];
    __syncthreads();
    {
        float f[11];
        #pragma unroll
        for (int i = 0; i < 11; ++i) f[i] = 0.f;
        const float* W2 = ws + WN2L_O;
        #pragma unroll 4
        for (int kq = 0; kq < 16; ++kq) {
            float bq[4];
            #pragma unroll
            for (int kk = 0; kk < 4; ++kk) bq[kk] = W2[(kq * 4 + kk) * 64 + lane];
            #pragma unroll
            for (int i = 0; i < 11; ++i) {
                float4 a4 = *(const float4*)&cS[(wr + i) * 68 + kq * 4];
                f[i] += a4.x * bq[0] + a4.y * bq[1] + a4.z * bq[2] + a4.w * bq[3];
            }
        }
        #pragma unroll
        for (int i = 0; i < 11; ++i)
            out[(size_t)(rowBlk + wr + i) * 576 + 512 + lane] = f[i];
    }
}

extern "C" void kernel_launch(void* const* d_in, const int* in_sizes, int n_in,
                              void* d_out, int out_size, void* d_ws, size_t ws_size,
                              hipStream_t stream) {
    (void)in_sizes; (void)n_in; (void)out_size; (void)ws_size;
    const float* in     = (const float*)d_in[0];
    const float* W_in   = (const float*)d_in[1];
    const float* b_in   = (const float*)d_in[2];
    const float* W_pos  = (const float*)d_in[3];
    const float* b_pos  = (const float*)d_in[4];
    const float* W_fc2  = (const float*)d_in[5];
    const float* b_fc2  = (const float*)d_in[6];
    const float* W_fc3  = (const float*)d_in[7];
    const float* b_fc3  = (const float*)d_in[8];
    const float* Wh1    = (const float*)d_in[9];
    const float* We1    = (const float*)d_in[10];
    const float* Wn1    = (const float*)d_in[11];
    const float* Wh2    = (const float*)d_in[12];
    const float* We2    = (const float*)d_in[13];
    const float* Wn2    = (const float*)d_in[14];
    const float* W_line = (const float*)d_in[15];
    float* out = (float*)d_out;
    float* ws  = (float*)d_ws;

    k_preAB<<<224, TPB, 0, stream>>>(W_in, b_in, W_pos, b_pos, Wn2, W_line, ws);
    k_preC<<<264, TPB, 0, stream>>>(W_fc2, b_fc2, ws);
    k_preD<<<344, TPB, 0, stream>>>(W_fc3, b_fc3, ws);
    k_preE<<<172, TPB, 0, stream>>>(Wh1, Wh2, ws);
    k_fused<<<B_ / 4, TPB, 0, stream>>>(in, We1, We2, Wn1, ws, out);
}

// Round 6
// 202.623 us; speedup vs baseline: 1.5462x; 1.5462x over previous
//
#include <hip/hip_runtime.h>

#define TPB 256
#define TPM 192   // k_main block size (3 waves)

// Problem dims
constexpr int B_ = 4096, A_ = 11;
constexpr int R_ = B_ * A_;       // 45056 rows

// ws offsets (floats). MH2/BH2 alias regions dead after preC.
constexpr int M_O     = 0;        // 8192   folded through fc2 (32x256)
constexpr int M2_O    = 8192;     // 8192   folded through fc3 (32x256)
constexpr int WC_O    = 16384;    // 1024   W_in @ W_pos_top       [dead after preC]
constexpr int XB_O    = 19712;    // 2048   per-timestep bias      [dead after preC]
constexpr int CB_O    = 21760;    // 256
constexpr int B2_O    = 22016;    // 2816   per-agent bias (11x256)
constexpr int WN2L_O  = 24832;    // 4096   Wn2 @ W_line (64x64)
constexpr int MH1_O   = 28928;    // 2048   M2 @ Wh1 (32x64)
constexpr int BH1_O   = 30976;    // 704
constexpr int MH2_O   = 16384;    // 2048   (aliases WC, dead by preE)
constexpr int BH2_O   = 18432;    // 704    (aliases dead gap)

// ================= pre kernels: wide split-K folds (unchanged, passing) =================

__global__ __launch_bounds__(TPB) void k_preAB(const float* __restrict__ Win,
                                               const float* __restrict__ bin,
                                               const float* __restrict__ Wpos,
                                               const float* __restrict__ bpos,
                                               const float* __restrict__ Wn2,
                                               const float* __restrict__ Wline,
                                               float* __restrict__ ws) {
    __shared__ float red[8 * 33];
    const int t = threadIdx.x, o8 = t & 31, ks = t >> 5;
    const int bx = blockIdx.x;
    if (bx < 32) {                       // Wc[i][j], 1024 outs, K=256
        int o = bx * 32 + o8, i = o >> 8, j = o & 255;
        const float* Ar = Win + i * 256;
        float p = 0.f;
        #pragma unroll 8
        for (int d = ks * 32; d < ks * 32 + 32; ++d) p += Ar[d] * Wpos[d * 256 + j];
        red[ks * 33 + o8] = p;
        __syncthreads();
        if (t < 32) {
            float s = 0.f;
            #pragma unroll
            for (int m = 0; m < 8; ++m) s += red[m * 33 + t];
            ws[WC_O + bx * 32 + t] = s;
        }
    } else if (bx < 96) {                // xb[l][j], 2048 outs, K=512 (bin then pe inline)
        int o = (bx - 32) * 32 + o8, l = o >> 8, j = o & 255;
        const float c0 = -logf(10000.f) / 256.f;
        float p = 0.f;
        for (int d = ks * 64; d < ks * 64 + 64; ++d) {
            float a;
            if (d < 256) a = bin[d];
            else {
                int dd = d - 256;
                float freq = expf((float)(dd & ~1) * c0);
                float ang = (float)l * freq;
                a = (dd & 1) ? cosf(ang) : sinf(ang);
            }
            p += a * Wpos[d * 256 + j];
        }
        red[ks * 33 + o8] = p;
        __syncthreads();
        if (t < 32) {
            int oo = (bx - 32) * 32 + t;
            float s = bpos[oo & 255];
            #pragma unroll
            for (int m = 0; m < 8; ++m) s += red[m * 33 + t];
            ws[XB_O + oo] = s;
        }
    } else {                             // Wn2L = Wn2 @ W_line, 4096 outs, 128 blocks
        int o = (bx - 96) * 32 + o8, k = o >> 6, c = o & 63;
        const float* Ar = Wn2 + k * 256;
        float p = 0.f;
        #pragma unroll 8
        for (int d = ks * 32; d < ks * 32 + 32; ++d) p += Ar[d] * Wline[d * 64 + c];
        red[ks * 33 + o8] = p;
        __syncthreads();
        if (t < 32) {
            float s = 0.f;
            #pragma unroll
            for (int m = 0; m < 8; ++m) s += red[m * 33 + t];
            ws[WN2L_O + (bx - 96) * 32 + t] = s;
        }
    }
}

__global__ __launch_bounds__(TPB) void k_preC(const float* __restrict__ Wfc2,
                                              const float* __restrict__ bfc2,
                                              float* __restrict__ ws) {
    __shared__ float red[8 * 33];
    const int t = threadIdx.x, o8 = t & 31, ks = t >> 5;
    const int bx = blockIdx.x;
    if (bx < 256) {                      // M[k][j], 8192 outs, K=256; k=(l,i)
        int o = bx * 32 + o8, k = o >> 8, j = o & 255;
        int l = k >> 2, i = k & 3;
        const float* Ar = ws + WC_O + i * 256;
        const float* Br = Wfc2 + l * 65536 + j;
        float p = 0.f;
        #pragma unroll 8
        for (int d = ks * 32; d < ks * 32 + 32; ++d) p += Ar[d] * Br[d * 256];
        red[ks * 33 + o8] = p;
        __syncthreads();
        if (t < 32) {
            float s = 0.f;
            #pragma unroll
            for (int m = 0; m < 8; ++m) s += red[m * 33 + t];
            ws[M_O + bx * 32 + t] = s;
        }
    } else {                             // cb[j], 256 outs, K=2048
        int j = (bx - 256) * 32 + o8;
        const float* Ar = ws + XB_O;
        float p = 0.f;
        #pragma unroll 4
        for (int dk = ks * 256; dk < ks * 256 + 256; ++dk) p += Ar[dk] * Wfc2[dk * 256 + j];
        red[ks * 33 + o8] = p;
        __syncthreads();
        if (t < 32) {
            int jj = (bx - 256) * 32 + t;
            float s = bfc2[jj];
            #pragma unroll
            for (int m = 0; m < 8; ++m) s += red[m * 33 + t];
            ws[CB_O + jj] = s;
        }
    }
}

__global__ __launch_bounds__(TPB) void k_preD(const float* __restrict__ Wfc3,
                                              const float* __restrict__ bfc3,
                                              float* __restrict__ ws) {
    __shared__ float red[8 * 33];
    const int t = threadIdx.x, o8 = t & 31, ks = t >> 5;
    const int bx = blockIdx.x;
    if (bx < 256) {                      // M2 = M @ Wfc3_top, 8192 outs
        int o = bx * 32 + o8, k = o >> 8, j = o & 255;
        const float* Ar = ws + M_O + k * 256;
        float p = 0.f;
        #pragma unroll 8
        for (int d = ks * 32; d < ks * 32 + 32; ++d) p += Ar[d] * Wfc3[d * 256 + j];
        red[ks * 33 + o8] = p;
        __syncthreads();
        if (t < 32) {
            float s = 0.f;
            #pragma unroll
            for (int m = 0; m < 8; ++m) s += red[m * 33 + t];
            ws[M2_O + bx * 32 + t] = s;
        }
    } else {                             // bias2[a][j], 2816 outs (88 blocks)
        int o = (bx - 256) * 32 + o8, j = o & 255;
        const float* Ar = ws + CB_O;
        float p = 0.f;
        #pragma unroll 8
        for (int d = ks * 32; d < ks * 32 + 32; ++d) p += Ar[d] * Wfc3[d * 256 + j];
        red[ks * 33 + o8] = p;
        __syncthreads();
        if (t < 32) {
            int oo = (bx - 256) * 32 + t;
            int aa = oo >> 8, jj = oo & 255;
            float s = bfc3[jj] + Wfc3[(256 + aa) * 256 + jj];
            #pragma unroll
            for (int m = 0; m < 8; ++m) s += red[m * 33 + t];
            ws[B2_O + oo] = s;
        }
    }
}

__global__ __launch_bounds__(TPB) void k_preE(const float* __restrict__ Wh1,
                                              const float* __restrict__ Wh2,
                                              float* __restrict__ ws) {
    __shared__ float red[8 * 33];
    const int t = threadIdx.x, o8 = t & 31, ks = t >> 5;
    const int bx = blockIdx.x;
    const float* Bw;  int oo_base;  int out_o;  int mode;
    if (bx < 64)       { mode = 0; out_o = MH1_O; oo_base = bx * 32;         Bw = Wh1; }
    else if (bx < 86)  { mode = 1; out_o = BH1_O; oo_base = (bx - 64) * 32;  Bw = Wh1; }
    else if (bx < 150) { mode = 0; out_o = MH2_O; oo_base = (bx - 86) * 32;  Bw = Wh2; }
    else               { mode = 1; out_o = BH2_O; oo_base = (bx - 150) * 32; Bw = Wh2; }
    int o = oo_base + o8;
    int r = o >> 6, c = o & 63;
    const float* Aw = ws + (mode == 0 ? M2_O : B2_O) + r * 256;
    float p = 0.f;
    #pragma unroll 8
    for (int d = ks * 32; d < ks * 32 + 32; ++d) p += Aw[d] * Bw[d * 64 + c];
    red[ks * 33 + o8] = p;
    __syncthreads();
    if (t < 32) {
        float s = 0.f;
        #pragma unroll
        for (int m = 0; m < 8; ++m) s += red[m * 33 + t];
        ws[out_o + oo_base + t] = s;
    }
}

// ================= k_main: 44 rows = 4 scenes per block; everything fused =================
// 192 threads: rg = t>>4 (0..11, rg<11 active in GEMMs), cg = t&15.
// 256-col GEMMs: thread cols = cg*4 + j*64 (2-way-free LDS B-reads).

__global__ __launch_bounds__(TPM) void k_main(const float* __restrict__ in,
                                              const float* __restrict__ We1g,
                                              const float* __restrict__ We2g,
                                              const float* __restrict__ Wn1,
                                              const float* __restrict__ ws,
                                              float* out) {
    __shared__ float inS[44 * 36];     // 6336 B
    __shared__ float work[44 * 68];    // 11968 B: h / agg2
    __shared__ float vS[44 * 68];      // 11968 B
    __shared__ float agg1S[44 * 68];   // 11968 B
    __shared__ float Bs[2048];         // 8192 B
    __shared__ float dcS[484];         // dots then corr (in-place)
    __shared__ float thrS[4];
    const int t = threadIdx.x;
    const int rg = t >> 4, cg = t & 15;
    const int r0 = rg * 4, c0 = cg * 4;
    const int rowBlk = blockIdx.x * 44;
    const bool act = rg < 11;

    // ---- stage input rows ----
    for (int o = t; o < 352; o += TPM) {
        int row = o >> 3, c4 = o & 7;
        *(float4*)&inS[row * 36 + c4 * 4] =
            *(const float4*)&in[(size_t)(rowBlk + row) * 32 + c4 * 4];
    }
    __syncthreads();

    // ---- ftraj = in @ M2 + bias2 -> out[:,0:256] ----
    {
        float acc[4][16];
        #pragma unroll
        for (int r = 0; r < 4; ++r)
            #pragma unroll
            for (int c = 0; c < 16; ++c) acc[r][c] = 0.f;
        for (int kh = 0; kh < 4; ++kh) {
            if (kh) __syncthreads();
            for (int o = t; o < 512; o += TPM)
                ((float4*)Bs)[o] = ((const float4*)(ws + M2_O + kh * 2048))[o];
            __syncthreads();
            if (act) {
                #pragma unroll
                for (int kq = 0; kq < 2; ++kq) {
                    float av[4][4];
                    #pragma unroll
                    for (int r = 0; r < 4; ++r) {
                        float4 a4 = *(const float4*)&inS[(r0 + r) * 36 + kh * 8 + kq * 4];
                        av[r][0] = a4.x; av[r][1] = a4.y; av[r][2] = a4.z; av[r][3] = a4.w;
                    }
                    #pragma unroll
                    for (int kk = 0; kk < 4; ++kk) {
                        float4 b[4];
                        #pragma unroll
                        for (int j = 0; j < 4; ++j)
                            b[j] = *(const float4*)&Bs[(kq * 4 + kk) * 256 + c0 + j * 64];
                        #pragma unroll
                        for (int r = 0; r < 4; ++r) {
                            float a = av[r][kk];
                            #pragma unroll
                            for (int j = 0; j < 4; ++j) {
                                acc[r][j * 4 + 0] += a * b[j].x;
                                acc[r][j * 4 + 1] += a * b[j].y;
                                acc[r][j * 4 + 2] += a * b[j].z;
                                acc[r][j * 4 + 3] += a * b[j].w;
                            }
                        }
                    }
                }
            }
        }
        if (act) {
            #pragma unroll
            for (int r = 0; r < 4; ++r) {
                int row = r0 + r, ag = row % 11;
                size_t ob = (size_t)(rowBlk + row) * 576;
                #pragma unroll
                for (int j = 0; j < 4; ++j) {
                    float4 b2 = *(const float4*)&ws[B2_O + ag * 256 + c0 + j * 64];
                    *(float4*)&out[ob + c0 + j * 64] =
                        make_float4(acc[r][j * 4 + 0] + b2.x, acc[r][j * 4 + 1] + b2.y,
                                    acc[r][j * 4 + 2] + b2.z, acc[r][j * 4 + 3] + b2.w);
                }
            }
        }
    }
    __syncthreads();   // drain out-writes (block-coherent read-back below)

    // ---- dots: 264 symmetric items, read ft back from out (L1/L2-hot) ----
    #pragma unroll 2
    for (int rep = 0; rep < 2; ++rep) {
        int idx = t + rep * TPM;
        if (idx < 264) {
            int s = idx / 66, p = idx % 66;
            int i = 0, q = p;
            while (q >= 11 - i) { q -= 11 - i; ++i; }
            int j = i + q;
            const float* ra = out + (size_t)(rowBlk + s * 11 + i) * 576;
            const float* rb = out + (size_t)(rowBlk + s * 11 + j) * 576;
            float d = 0.f;
            #pragma unroll 16
            for (int c = 0; c < 64; ++c) {
                float4 a = *(const float4*)&ra[c * 4];
                float4 b = *(const float4*)&rb[c * 4];
                d += a.x * b.x + a.y * b.y + a.z * b.z + a.w * b.w;
            }
            dcS[s * 121 + i * 11 + j] = d;
            dcS[s * 121 + j * 11 + i] = d;
        }
    }
    __syncthreads();

    // ---- corr (in-place over dots) + per-scene threshold ----
    {
        float cc0 = 0.f, cc1 = 0.f, cc2 = 0.f;
        int i0, j0, s0i, i1, j1, s1i, i2, j2, s2i;
        {
            int idx = t;            s0i = idx / 121; int p = idx % 121; i0 = p / 11; j0 = p % 11;
            cc0 = dcS[idx] * rsqrtf(dcS[s0i * 121 + i0 * 12] * dcS[s0i * 121 + j0 * 12]);
        }
        {
            int idx = t + TPM;      s1i = idx / 121; int p = idx % 121; i1 = p / 11; j1 = p % 11;
            cc1 = dcS[idx] * rsqrtf(dcS[s1i * 121 + i1 * 12] * dcS[s1i * 121 + j1 * 12]);
        }
        if (t + 2 * TPM < 484) {
            int idx = t + 2 * TPM;  s2i = idx / 121; int p = idx % 121; i2 = p / 11; j2 = p % 11;
            cc2 = dcS[idx] * rsqrtf(dcS[s2i * 121 + i2 * 12] * dcS[s2i * 121 + j2 * 12]);
        }
        __syncthreads();
        dcS[t] = cc0;
        dcS[t + TPM] = cc1;
        if (t + 2 * TPM < 484) dcS[t + 2 * TPM] = cc2;
    }
    __syncthreads();
    if (t < 4) {
        float mn = 3.0e38f;
        for (int p = 0; p < 121; ++p) mn = fminf(mn, dcS[t * 121 + p]);
        thrS[t] = (mn < 0.4f) ? 0.4f : ((mn > 0.4f && mn < 0.6f) ? mn + 0.1f : mn + 0.03f);
    }

    // ---- two NMP stages ----
    for (int st = 0; st < 2; ++st) {
        const float* bh = ws + (st ? BH2_O : BH1_O);
        const float* We = st ? We2g : We1g;
        __syncthreads();
        for (int o = t; o < 512; o += TPM)
            ((float4*)Bs)[o] = ((const float4*)(ws + (st ? MH2_O : MH1_O)))[o];
        __syncthreads();
        // h = relu(in @ Mh + bh)
        float hh[4][4];
        #pragma unroll
        for (int r = 0; r < 4; ++r)
            #pragma unroll
            for (int c = 0; c < 4; ++c) hh[r][c] = 0.f;
        if (act) {
            #pragma unroll
            for (int kq = 0; kq < 8; ++kq) {
                float av[4][4];
                #pragma unroll
                for (int r = 0; r < 4; ++r) {
                    float4 a4 = *(const float4*)&inS[(r0 + r) * 36 + kq * 4];
                    av[r][0] = a4.x; av[r][1] = a4.y; av[r][2] = a4.z; av[r][3] = a4.w;
                }
                #pragma unroll
                for (int kk = 0; kk < 4; ++kk) {
                    float4 b = *(const float4*)&Bs[(kq * 4 + kk) * 64 + c0];
                    #pragma unroll
                    for (int r = 0; r < 4; ++r) {
                        float a = av[r][kk];
                        hh[r][0] += a * b.x; hh[r][1] += a * b.y;
                        hh[r][2] += a * b.z; hh[r][3] += a * b.w;
                    }
                }
            }
        }
        __syncthreads();
        if (act) {
            #pragma unroll
            for (int r = 0; r < 4; ++r) {
                int row = r0 + r, ag = row % 11;
                float4 b = *(const float4*)&bh[ag * 64 + c0];
                *(float4*)&work[row * 68 + c0] =
                    make_float4(fmaxf(hh[r][0] + b.x, 0.f), fmaxf(hh[r][1] + b.y, 0.f),
                                fmaxf(hh[r][2] + b.z, 0.f), fmaxf(hh[r][3] + b.w, 0.f));
            }
        }
        __syncthreads();
        // u (regs), v (LDS) over 4 We chunks
        float uu[4][4], vv[4][4];
        #pragma unroll
        for (int r = 0; r < 4; ++r)
            #pragma unroll
            for (int c = 0; c < 4; ++c) { uu[r][c] = 0.f; vv[r][c] = 0.f; }
        for (int kh = 0; kh < 4; ++kh) {
            if (kh) __syncthreads();
            for (int o = t; o < 256; o += TPM) {
                ((float4*)Bs)[o] = ((const float4*)(We + kh * 1024))[o];
                ((float4*)Bs)[o + 256] = ((const float4*)(We + 4096 + kh * 1024))[o];
            }
            __syncthreads();
            if (act) {
                #pragma unroll
                for (int kq = 0; kq < 4; ++kq) {
                    float av[4][4];
                    #pragma unroll
                    for (int r = 0; r < 4; ++r) {
                        float4 a4 = *(const float4*)&work[(r0 + r) * 68 + kh * 16 + kq * 4];
                        av[r][0] = a4.x; av[r][1] = a4.y; av[r][2] = a4.z; av[r][3] = a4.w;
                    }
                    #pragma unroll
                    for (int kk = 0; kk < 4; ++kk) {
                        float4 bu = *(const float4*)&Bs[(kq * 4 + kk) * 64 + c0];
                        float4 bv = *(const float4*)&Bs[1024 + (kq * 4 + kk) * 64 + c0];
                        #pragma unroll
                        for (int r = 0; r < 4; ++r) {
                            float a = av[r][kk];
                            uu[r][0] += a * bu.x; uu[r][1] += a * bu.y;
                            uu[r][2] += a * bu.z; uu[r][3] += a * bu.w;
                            vv[r][0] += a * bv.x; vv[r][1] += a * bv.y;
                            vv[r][2] += a * bv.z; vv[r][3] += a * bv.w;
                        }
                    }
                }
            }
        }
        __syncthreads();
        if (act) {
            #pragma unroll
            for (int r = 0; r < 4; ++r)
                *(float4*)&vS[(r0 + r) * 68 + c0] =
                    make_float4(vv[r][0], vv[r][1], vv[r][2], vv[r][3]);
        }
        __syncthreads();
        // aggregation (u regs + v LDS + corr LDS)
        if (act) {
            #pragma unroll
            for (int r = 0; r < 4; ++r) {
                int row = r0 + r;
                int s = row / 11;
                int il = row - s * 11;
                float th = thrS[s];
                float t0 = 0.f, t1 = 0.f, t2 = 0.f, t3 = 0.f, cnt = 0.f;
                #pragma unroll
                for (int j = 0; j < 11; ++j) {
                    float4 vj = *(const float4*)&vS[(s * 11 + j) * 68 + c0];
                    if (st == 0) {
                        t0 += fmaxf(uu[r][0] + vj.x, 0.f);
                        t1 += fmaxf(uu[r][1] + vj.y, 0.f);
                        t2 += fmaxf(uu[r][2] + vj.z, 0.f);
                        t3 += fmaxf(uu[r][3] + vj.w, 0.f);
                    } else {
                        float adj = (dcS[s * 121 + il * 11 + j] >= th) ? 1.f : 0.f;
                        t0 += adj * fmaxf(uu[r][0] + vj.x, 0.f);
                        t1 += adj * fmaxf(uu[r][1] + vj.y, 0.f);
                        t2 += adj * fmaxf(uu[r][2] + vj.z, 0.f);
                        t3 += adj * fmaxf(uu[r][3] + vj.w, 0.f);
                        cnt += adj;
                    }
                }
                float inv = (st == 0) ? (1.f / 11.f) : (1.f / (cnt + 1e-6f));
                float4 res = make_float4(t0 * inv, t1 * inv, t2 * inv, t3 * inv);
                if (st == 0) *(float4*)&agg1S[row * 68 + c0] = res;
                else         *(float4*)&work[row * 68 + c0] = res;
            }
        }
    }
    __syncthreads();

    // ---- inter = agg1 @ Wn1 -> out[:,256:512] ----
    {
        float acc[4][16];
        #pragma unroll
        for (int r = 0; r < 4; ++r)
            #pragma unroll
            for (int c = 0; c < 16; ++c) acc[r][c] = 0.f;
        for (int kh = 0; kh < 8; ++kh) {
            if (kh) __syncthreads();
            for (int o = t; o < 512; o += TPM)
                ((float4*)Bs)[o] = ((const float4*)(Wn1 + kh * 2048))[o];
            __syncthreads();
            if (act) {
                #pragma unroll
                for (int kq = 0; kq < 2; ++kq) {
                    float av[4][4];
                    #pragma unroll
                    for (int r = 0; r < 4; ++r) {
                        float4 a4 = *(const float4*)&agg1S[(r0 + r) * 68 + kh * 8 + kq * 4];
                        av[r][0] = a4.x; av[r][1] = a4.y; av[r][2] = a4.z; av[r][3] = a4.w;
                    }
                    #pragma unroll
                    for (int kk = 0; kk < 4; ++kk) {
                        float4 b[4];
                        #pragma unroll
                        for (int j = 0; j < 4; ++j)
                            b[j] = *(const float4*)&Bs[(kq * 4 + kk) * 256 + c0 + j * 64];
                        #pragma unroll
                        for (int r = 0; r < 4; ++r) {
                            float a = av[r][kk];
                            #pragma unroll
                            for (int j = 0; j < 4; ++j) {
                                acc[r][j * 4 + 0] += a * b[j].x;
                                acc[r][j * 4 + 1] += a * b[j].y;
                                acc[r][j * 4 + 2] += a * b[j].z;
                                acc[r][j * 4 + 3] += a * b[j].w;
                            }
                        }
                    }
                }
            }
        }
        if (act) {
            #pragma unroll
            for (int r = 0; r < 4; ++r) {
                size_t ob = (size_t)(rowBlk + r0 + r) * 576 + 256;
                #pragma unroll
                for (int j = 0; j < 4; ++j)
                    *(float4*)&out[ob + c0 + j * 64] =
                        make_float4(acc[r][j * 4 + 0], acc[r][j * 4 + 1],
                                    acc[r][j * 4 + 2], acc[r][j * 4 + 3]);
            }
        }
    }

    // ---- feat = agg2 @ Wn2L -> out[:,512:576] ----
    {
        float fa[4][4];
        #pragma unroll
        for (int r = 0; r < 4; ++r)
            #pragma unroll
            for (int c = 0; c < 4; ++c) fa[r][c] = 0.f;
        for (int kh = 0; kh < 2; ++kh) {
            __syncthreads();
            for (int o = t; o < 512; o += TPM)
                ((float4*)Bs)[o] = ((const float4*)(ws + WN2L_O + kh * 2048))[o];
            __syncthreads();
            if (act) {
                #pragma unroll
                for (int kq = 0; kq < 8; ++kq) {
                    float av[4][4];
                    #pragma unroll
                    for (int r = 0; r < 4; ++r) {
                        float4 a4 = *(const float4*)&work[(r0 + r) * 68 + kh * 32 + kq * 4];
                        av[r][0] = a4.x; av[r][1] = a4.y; av[r][2] = a4.z; av[r][3] = a4.w;
                    }
                    #pragma unroll
                    for (int kk = 0; kk < 4; ++kk) {
                        float4 b = *(const float4*)&Bs[(kq * 4 + kk) * 64 + c0];
                        #pragma unroll
                        for (int r = 0; r < 4; ++r) {
                            float a = av[r][kk];
                            fa[r][0] += a * b.x; fa[r][1] += a * b.y;
                            fa[r][2] += a * b.z; fa[r][3] += a * b.w;
                        }
                    }
                }
            }
        }
        if (act) {
            #pragma unroll
            for (int r = 0; r < 4; ++r)
                *(float4*)&out[(size_t)(rowBlk + r0 + r) * 576 + 512 + c0] =
                    make_float4(fa[r][0], fa[r][1], fa[r][2], fa[r][3]);
        }
    }
}

extern "C" void kernel_launch(void* const* d_in, const int* in_sizes, int n_in,
                              void* d_out, int out_size, void* d_ws, size_t ws_size,
                              hipStream_t stream) {
    (void)in_sizes; (void)n_in; (void)out_size; (void)ws_size;
    const float* in     = (const float*)d_in[0];
    const float* W_in   = (const float*)d_in[1];
    const float* b_in   = (const float*)d_in[2];
    const float* W_pos  = (const float*)d_in[3];
    const float* b_pos  = (const float*)d_in[4];
    const float* W_fc2  = (const float*)d_in[5];
    const float* b_fc2  = (const float*)d_in[6];
    const float* W_fc3  = (const float*)d_in[7];
    const float* b_fc3  = (const float*)d_in[8];
    const float* Wh1    = (const float*)d_in[9];
    const float* We1    = (const float*)d_in[10];
    const float* Wn1    = (const float*)d_in[11];
    const float* Wh2    = (const float*)d_in[12];
    const float* We2    = (const float*)d_in[13];
    const float* Wn2    = (const float*)d_in[14];
    const float* W_line = (const float*)d_in[15];
    float* out = (float*)d_out;
    float* ws  = (float*)d_ws;

    k_preAB<<<224, TPB, 0, stream>>>(W_in, b_in, W_pos, b_pos, Wn2, W_line, ws);
    k_preC<<<264, TPB, 0, stream>>>(W_fc2, b_fc2, ws);
    k_preD<<<344, TPB, 0, stream>>>(W_fc3, b_fc3, ws);
    k_preE<<<172, TPB, 0, stream>>>(Wh1, Wh2, ws);
    k_main<<<B_ / 4, TPM, 0, stream>>>(in, We1, We2, Wn1, ws, out);
}

// Round 7
// 168.102 us; speedup vs baseline: 1.8637x; 1.2054x over previous
//
#include <hip/hip_runtime.h>

#define TPB 256
#define TPM 192   // k_main block size (3 waves)

// Problem dims
constexpr int B_ = 4096, A_ = 11;
constexpr int R_ = B_ * A_;       // 45056 rows

// ws offsets (floats). MH2/BH2 alias regions dead after preC.
constexpr int M_O     = 0;        // 8192   folded through fc2 (32x256)
constexpr int M2_O    = 8192;     // 8192   folded through fc3 (32x256)
constexpr int WC_O    = 16384;    // 1024   W_in @ W_pos_top       [dead after preC]
constexpr int XB_O    = 19712;    // 2048   per-timestep bias      [dead after preC]
constexpr int CB_O    = 21760;    // 256
constexpr int B2_O    = 22016;    // 2816   per-agent bias (11x256)
constexpr int WN2L_O  = 24832;    // 4096   Wn2 @ W_line (64x64)
constexpr int MH1_O   = 28928;    // 2048   M2 @ Wh1 (32x64)
constexpr int BH1_O   = 30976;    // 704
constexpr int MH2_O   = 16384;    // 2048   (aliases WC, dead by preE)
constexpr int BH2_O   = 18432;    // 704    (aliases dead gap)

// ================= pre kernels: wide split-K folds (unchanged, passing) =================

__global__ __launch_bounds__(TPB) void k_preAB(const float* __restrict__ Win,
                                               const float* __restrict__ bin,
                                               const float* __restrict__ Wpos,
                                               const float* __restrict__ bpos,
                                               const float* __restrict__ Wn2,
                                               const float* __restrict__ Wline,
                                               float* __restrict__ ws) {
    __shared__ float red[8 * 33];
    const int t = threadIdx.x, o8 = t & 31, ks = t >> 5;
    const int bx = blockIdx.x;
    if (bx < 32) {                       // Wc[i][j], 1024 outs, K=256
        int o = bx * 32 + o8, i = o >> 8, j = o & 255;
        const float* Ar = Win + i * 256;
        float p = 0.f;
        #pragma unroll 8
        for (int d = ks * 32; d < ks * 32 + 32; ++d) p += Ar[d] * Wpos[d * 256 + j];
        red[ks * 33 + o8] = p;
        __syncthreads();
        if (t < 32) {
            float s = 0.f;
            #pragma unroll
            for (int m = 0; m < 8; ++m) s += red[m * 33 + t];
            ws[WC_O + bx * 32 + t] = s;
        }
    } else if (bx < 96) {                // xb[l][j], 2048 outs, K=512 (bin then pe inline)
        int o = (bx - 32) * 32 + o8, l = o >> 8, j = o & 255;
        const float c0 = -logf(10000.f) / 256.f;
        float p = 0.f;
        for (int d = ks * 64; d < ks * 64 + 64; ++d) {
            float a;
            if (d < 256) a = bin[d];
            else {
                int dd = d - 256;
                float freq = expf((float)(dd & ~1) * c0);
                float ang = (float)l * freq;
                a = (dd & 1) ? cosf(ang) : sinf(ang);
            }
            p += a * Wpos[d * 256 + j];
        }
        red[ks * 33 + o8] = p;
        __syncthreads();
        if (t < 32) {
            int oo = (bx - 32) * 32 + t;
            float s = bpos[oo & 255];
            #pragma unroll
            for (int m = 0; m < 8; ++m) s += red[m * 33 + t];
            ws[XB_O + oo] = s;
        }
    } else {                             // Wn2L = Wn2 @ W_line, 4096 outs, 128 blocks
        int o = (bx - 96) * 32 + o8, k = o >> 6, c = o & 63;
        const float* Ar = Wn2 + k * 256;
        float p = 0.f;
        #pragma unroll 8
        for (int d = ks * 32; d < ks * 32 + 32; ++d) p += Ar[d] * Wline[d * 64 + c];
        red[ks * 33 + o8] = p;
        __syncthreads();
        if (t < 32) {
            float s = 0.f;
            #pragma unroll
            for (int m = 0; m < 8; ++m) s += red[m * 33 + t];
            ws[WN2L_O + (bx - 96) * 32 + t] = s;
        }
    }
}

__global__ __launch_bounds__(TPB) void k_preC(const float* __restrict__ Wfc2,
                                              const float* __restrict__ bfc2,
                                              float* __restrict__ ws) {
    __shared__ float red[8 * 33];
    const int t = threadIdx.x, o8 = t & 31, ks = t >> 5;
    const int bx = blockIdx.x;
    if (bx < 256) {                      // M[k][j], 8192 outs, K=256; k=(l,i)
        int o = bx * 32 + o8, k = o >> 8, j = o & 255;
        int l = k >> 2, i = k & 3;
        const float* Ar = ws + WC_O + i * 256;
        const float* Br = Wfc2 + l * 65536 + j;
        float p = 0.f;
        #pragma unroll 8
        for (int d = ks * 32; d < ks * 32 + 32; ++d) p += Ar[d] * Br[d * 256];
        red[ks * 33 + o8] = p;
        __syncthreads();
        if (t < 32) {
            float s = 0.f;
            #pragma unroll
            for (int m = 0; m < 8; ++m) s += red[m * 33 + t];
            ws[M_O + bx * 32 + t] = s;
        }
    } else {                             // cb[j], 256 outs, K=2048
        int j = (bx - 256) * 32 + o8;
        const float* Ar = ws + XB_O;
        float p = 0.f;
        #pragma unroll 4
        for (int dk = ks * 256; dk < ks * 256 + 256; ++dk) p += Ar[dk] * Wfc2[dk * 256 + j];
        red[ks * 33 + o8] = p;
        __syncthreads();
        if (t < 32) {
            int jj = (bx - 256) * 32 + t;
            float s = bfc2[jj];
            #pragma unroll
            for (int m = 0; m < 8; ++m) s += red[m * 33 + t];
            ws[CB_O + jj] = s;
        }
    }
}

__global__ __launch_bounds__(TPB) void k_preD(const float* __restrict__ Wfc3,
                                              const float* __restrict__ bfc3,
                                              float* __restrict__ ws) {
    __shared__ float red[8 * 33];
    const int t = threadIdx.x, o8 = t & 31, ks = t >> 5;
    const int bx = blockIdx.x;
    if (bx < 256) {                      // M2 = M @ Wfc3_top, 8192 outs
        int o = bx * 32 + o8, k = o >> 8, j = o & 255;
        const float* Ar = ws + M_O + k * 256;
        float p = 0.f;
        #pragma unroll 8
        for (int d = ks * 32; d < ks * 32 + 32; ++d) p += Ar[d] * Wfc3[d * 256 + j];
        red[ks * 33 + o8] = p;
        __syncthreads();
        if (t < 32) {
            float s = 0.f;
            #pragma unroll
            for (int m = 0; m < 8; ++m) s += red[m * 33 + t];
            ws[M2_O + bx * 32 + t] = s;
        }
    } else {                             // bias2[a][j], 2816 outs (88 blocks)
        int o = (bx - 256) * 32 + o8, j = o & 255;
        const float* Ar = ws + CB_O;
        float p = 0.f;
        #pragma unroll 8
        for (int d = ks * 32; d < ks * 32 + 32; ++d) p += Ar[d] * Wfc3[d * 256 + j];
        red[ks * 33 + o8] = p;
        __syncthreads();
        if (t < 32) {
            int oo = (bx - 256) * 32 + t;
            int aa = oo >> 8, jj = oo & 255;
            float s = bfc3[jj] + Wfc3[(256 + aa) * 256 + jj];
            #pragma unroll
            for (int m = 0; m < 8; ++m) s += red[m * 33 + t];
            ws[B2_O + oo] = s;
        }
    }
}

__global__ __launch_bounds__(TPB) void k_preE(const float* __restrict__ Wh1,
                                              const float* __restrict__ Wh2,
                                              float* __restrict__ ws) {
    __shared__ float red[8 * 33];
    const int t = threadIdx.x, o8 = t & 31, ks = t >> 5;
    const int bx = blockIdx.x;
    const float* Bw;  int oo_base;  int out_o;  int mode;
    if (bx < 64)       { mode = 0; out_o = MH1_O; oo_base = bx * 32;         Bw = Wh1; }
    else if (bx < 86)  { mode = 1; out_o = BH1_O; oo_base = (bx - 64) * 32;  Bw = Wh1; }
    else if (bx < 150) { mode = 0; out_o = MH2_O; oo_base = (bx - 86) * 32;  Bw = Wh2; }
    else               { mode = 1; out_o = BH2_O; oo_base = (bx - 150) * 32; Bw = Wh2; }
    int o = oo_base + o8;
    int r = o >> 6, c = o & 63;
    const float* Aw = ws + (mode == 0 ? M2_O : B2_O) + r * 256;
    float p = 0.f;
    #pragma unroll 8
    for (int d = ks * 32; d < ks * 32 + 32; ++d) p += Aw[d] * Bw[d * 64 + c];
    red[ks * 33 + o8] = p;
    __syncthreads();
    if (t < 32) {
        float s = 0.f;
        #pragma unroll
        for (int m = 0; m < 8; ++m) s += red[m * 33 + t];
        ws[out_o + oo_base + t] = s;
    }
}

// ================= k_main: 44 rows = 4 scenes/block, prefetched staging, 2 LDS buffers =================

__global__ __launch_bounds__(TPM) void k_main(const float* __restrict__ in,
                                              const float* __restrict__ We1g,
                                              const float* __restrict__ We2g,
                                              const float* __restrict__ Wn1,
                                              const float* __restrict__ ws,
                                              float* out) {
    __shared__ float inS[44 * 36];     // 6336 B
    __shared__ float bufA[44 * 68];    // 11968 B
    __shared__ float bufB[44 * 68];    // 11968 B
    __shared__ float Bs[2048];         // 8192 B
    __shared__ float dcS[484];         // dots -> corr in-place
    __shared__ float thrS[4];
    const int t = threadIdx.x;
    const int rg = t >> 4, cg = t & 15;
    const int r0 = rg * 4, c0 = cg * 4;
    const int rowBlk = blockIdx.x * 44;
    const bool act = rg < 11;

    float4 pf0, pf1, pf2;
    auto pfLoad = [&](const float4* lo, const float4* hi) {
        pf0 = lo[t];
        pf1 = (t < 64) ? lo[t + 192] : hi[t - 64];
        if (t < 128) pf2 = hi[t + 128];
    };
    auto pfStore = [&]() {
        float4* d = (float4*)Bs;
        d[t] = pf0; d[t + 192] = pf1;
        if (t < 128) d[t + 384] = pf2;
    };

    // prefetch M2 chunk 0; stage input rows
    pfLoad((const float4*)(ws + M2_O), (const float4*)(ws + M2_O) + 256);
    for (int o = t; o < 352; o += TPM) {
        int row = o >> 3, c4 = o & 7;
        *(float4*)&inS[row * 36 + c4 * 4] =
            *(const float4*)&in[(size_t)(rowBlk + row) * 32 + c4 * 4];
    }
    __syncthreads();

    // ---- ftraj = in @ M2 + bias2 (acc in regs) ----
    float acc[4][16];
    #pragma unroll
    for (int r = 0; r < 4; ++r)
        #pragma unroll
        for (int c = 0; c < 16; ++c) acc[r][c] = 0.f;
    for (int kh = 0; kh < 4; ++kh) {
        pfStore();
        if (kh < 3) pfLoad((const float4*)(ws + M2_O) + (kh + 1) * 512,
                           (const float4*)(ws + M2_O) + (kh + 1) * 512 + 256);
        else        pfLoad((const float4*)(ws + MH1_O), (const float4*)(ws + MH1_O) + 256);
        __syncthreads();
        if (act) {
            #pragma unroll
            for (int kq = 0; kq < 2; ++kq) {
                float av[4][4];
                #pragma unroll
                for (int r = 0; r < 4; ++r) {
                    float4 a4 = *(const float4*)&inS[(r0 + r) * 36 + kh * 8 + kq * 4];
                    av[r][0] = a4.x; av[r][1] = a4.y; av[r][2] = a4.z; av[r][3] = a4.w;
                }
                #pragma unroll
                for (int kk = 0; kk < 4; ++kk) {
                    float4 b[4];
                    #pragma unroll
                    for (int j = 0; j < 4; ++j)
                        b[j] = *(const float4*)&Bs[(kq * 4 + kk) * 256 + c0 + j * 64];
                    #pragma unroll
                    for (int r = 0; r < 4; ++r) {
                        float a = av[r][kk];
                        #pragma unroll
                        for (int j = 0; j < 4; ++j) {
                            acc[r][j * 4 + 0] += a * b[j].x;
                            acc[r][j * 4 + 1] += a * b[j].y;
                            acc[r][j * 4 + 2] += a * b[j].z;
                            acc[r][j * 4 + 3] += a * b[j].w;
                        }
                    }
                }
            }
        }
        __syncthreads();
    }
    // bias + store ft -> out
    if (act) {
        #pragma unroll
        for (int r = 0; r < 4; ++r) {
            int row = r0 + r, il = row % 11;
            size_t ob = (size_t)(rowBlk + row) * 576;
            #pragma unroll
            for (int j = 0; j < 4; ++j) {
                float4 b2 = *(const float4*)&ws[B2_O + il * 256 + c0 + j * 64];
                acc[r][j * 4 + 0] += b2.x; acc[r][j * 4 + 1] += b2.y;
                acc[r][j * 4 + 2] += b2.z; acc[r][j * 4 + 3] += b2.w;
                *(float4*)&out[ob + c0 + j * 64] =
                    make_float4(acc[r][j * 4 + 0], acc[r][j * 4 + 1],
                                acc[r][j * 4 + 2], acc[r][j * 4 + 3]);
            }
        }
    }

    // ---- dots via 4 LDS slices of the register ft tile ----
    bool has0 = false, has1 = false;
    int s0_ = 0, i0_ = 0, j0_ = 0, s1_ = 0, i1_ = 0, j1_ = 0;
    {
        int idx = t;
        if (idx < 264) {
            has0 = true; s0_ = idx / 66; int p = idx % 66; int i = 0;
            while (p >= 11 - i) { p -= 11 - i; ++i; }
            i0_ = i; j0_ = i + p;
        }
        idx = t + TPM;
        if (idx < 264) {
            has1 = true; s1_ = idx / 66; int p = idx % 66; int i = 0;
            while (p >= 11 - i) { p -= 11 - i; ++i; }
            i1_ = i; j1_ = i + p;
        }
    }
    float dacc0 = 0.f, dacc1 = 0.f;
    for (int sl = 0; sl < 4; ++sl) {
        if (act) {
            #pragma unroll
            for (int r = 0; r < 4; ++r)
                *(float4*)&bufA[(r0 + r) * 68 + c0] =
                    make_float4(acc[r][sl * 4 + 0], acc[r][sl * 4 + 1],
                                acc[r][sl * 4 + 2], acc[r][sl * 4 + 3]);
        }
        __syncthreads();
        if (has0) {
            const float* ra = &bufA[(s0_ * 11 + i0_) * 68];
            const float* rb = &bufA[(s0_ * 11 + j0_) * 68];
            #pragma unroll
            for (int c = 0; c < 16; ++c) {
                float4 a = *(const float4*)&ra[c * 4];
                float4 b = *(const float4*)&rb[c * 4];
                dacc0 += a.x * b.x + a.y * b.y + a.z * b.z + a.w * b.w;
            }
        }
        if (has1) {
            const float* ra = &bufA[(s1_ * 11 + i1_) * 68];
            const float* rb = &bufA[(s1_ * 11 + j1_) * 68];
            #pragma unroll
            for (int c = 0; c < 16; ++c) {
                float4 a = *(const float4*)&ra[c * 4];
                float4 b = *(const float4*)&rb[c * 4];
                dacc1 += a.x * b.x + a.y * b.y + a.z * b.z + a.w * b.w;
            }
        }
        __syncthreads();
    }
    if (has0) { dcS[s0_ * 121 + i0_ * 11 + j0_] = dacc0;
                dcS[s0_ * 121 + j0_ * 11 + i0_] = dacc0; }
    if (has1) { dcS[s1_ * 121 + i1_ * 11 + j1_] = dacc1;
                dcS[s1_ * 121 + j1_ * 11 + i1_] = dacc1; }
    __syncthreads();

    // ---- corr (in-place) + per-scene threshold ----
    {
        float cc0, cc1, cc2 = 0.f;
        {
            int idx = t; int si = idx / 121, p = idx % 121, i = p / 11, j = p % 11;
            cc0 = dcS[idx] * rsqrtf(dcS[si * 121 + i * 12] * dcS[si * 121 + j * 12]);
        }
        {
            int idx = t + TPM; int si = idx / 121, p = idx % 121, i = p / 11, j = p % 11;
            cc1 = dcS[idx] * rsqrtf(dcS[si * 121 + i * 12] * dcS[si * 121 + j * 12]);
        }
        if (t + 2 * TPM < 484) {
            int idx = t + 2 * TPM; int si = idx / 121, p = idx % 121, i = p / 11, j = p % 11;
            cc2 = dcS[idx] * rsqrtf(dcS[si * 121 + i * 12] * dcS[si * 121 + j * 12]);
        }
        __syncthreads();
        dcS[t] = cc0;
        dcS[t + TPM] = cc1;
        if (t + 2 * TPM < 484) dcS[t + 2 * TPM] = cc2;
    }
    __syncthreads();
    if (t < 4) {
        float mn = 3.0e38f;
        for (int p = 0; p < 121; ++p) mn = fminf(mn, dcS[t * 121 + p]);
        thrS[t] = (mn < 0.4f) ? 0.4f : ((mn > 0.4f && mn < 0.6f) ? mn + 0.1f : mn + 0.03f);
    }
    __syncthreads();

    // ---- two NMP stages with ping-pong buffers ----
    float a1v[4][4];
    for (int st = 0; st < 2; ++st) {
        const float* bh = ws + (st ? BH2_O : BH1_O);
        const float* We = st ? We2g : We1g;
        float* hbuf = st ? bufB : bufA;
        pfStore();                                   // Mh (prefetched earlier)
        pfLoad((const float4*)(We), (const float4*)(We + 4096));
        __syncthreads();
        float hh[4][4];
        #pragma unroll
        for (int r = 0; r < 4; ++r)
            #pragma unroll
            for (int c = 0; c < 4; ++c) hh[r][c] = 0.f;
        if (act) {
            #pragma unroll
            for (int kq = 0; kq < 8; ++kq) {
                float av[4][4];
                #pragma unroll
                for (int r = 0; r < 4; ++r) {
                    float4 a4 = *(const float4*)&inS[(r0 + r) * 36 + kq * 4];
                    av[r][0] = a4.x; av[r][1] = a4.y; av[r][2] = a4.z; av[r][3] = a4.w;
                }
                #pragma unroll
                for (int kk = 0; kk < 4; ++kk) {
                    float4 b = *(const float4*)&Bs[(kq * 4 + kk) * 64 + c0];
                    #pragma unroll
                    for (int r = 0; r < 4; ++r) {
                        float a = av[r][kk];
                        hh[r][0] += a * b.x; hh[r][1] += a * b.y;
                        hh[r][2] += a * b.z; hh[r][3] += a * b.w;
                    }
                }
            }
            #pragma unroll
            for (int r = 0; r < 4; ++r) {
                int il = (r0 + r) % 11;
                float4 b = *(const float4*)&bh[il * 64 + c0];
                *(float4*)&hbuf[(r0 + r) * 68 + c0] =
                    make_float4(fmaxf(hh[r][0] + b.x, 0.f), fmaxf(hh[r][1] + b.y, 0.f),
                                fmaxf(hh[r][2] + b.z, 0.f), fmaxf(hh[r][3] + b.w, 0.f));
            }
        }
        __syncthreads();
        float uu[4][4], vv[4][4];
        #pragma unroll
        for (int r = 0; r < 4; ++r)
            #pragma unroll
            for (int c = 0; c < 4; ++c) { uu[r][c] = 0.f; vv[r][c] = 0.f; }
        for (int kh = 0; kh < 4; ++kh) {
            pfStore();
            if (kh < 3)
                pfLoad((const float4*)(We + (kh + 1) * 1024),
                       (const float4*)(We + 4096 + (kh + 1) * 1024));
            else if (st == 0)
                pfLoad((const float4*)(ws + MH2_O), (const float4*)(ws + MH2_O) + 256);
            else
                pfLoad((const float4*)(Wn1), (const float4*)(Wn1) + 256);
            __syncthreads();
            if (act) {
                #pragma unroll
                for (int kq = 0; kq < 4; ++kq) {
                    float av[4][4];
                    #pragma unroll
                    for (int r = 0; r < 4; ++r) {
                        float4 a4 = *(const float4*)&hbuf[(r0 + r) * 68 + kh * 16 + kq * 4];
                        av[r][0] = a4.x; av[r][1] = a4.y; av[r][2] = a4.z; av[r][3] = a4.w;
                    }
                    #pragma unroll
                    for (int kk = 0; kk < 4; ++kk) {
                        float4 bu = *(const float4*)&Bs[(kq * 4 + kk) * 64 + c0];
                        float4 bv = *(const float4*)&Bs[1024 + (kq * 4 + kk) * 64 + c0];
                        #pragma unroll
                        for (int r = 0; r < 4; ++r) {
                            float a = av[r][kk];
                            uu[r][0] += a * bu.x; uu[r][1] += a * bu.y;
                            uu[r][2] += a * bu.z; uu[r][3] += a * bu.w;
                            vv[r][0] += a * bv.x; vv[r][1] += a * bv.y;
                            vv[r][2] += a * bv.z; vv[r][3] += a * bv.w;
                        }
                    }
                }
            }
            __syncthreads();
        }
        if (act) {
            #pragma unroll
            for (int r = 0; r < 4; ++r)
                *(float4*)&bufB[(r0 + r) * 68 + c0] =
                    make_float4(vv[r][0], vv[r][1], vv[r][2], vv[r][3]);
        }
        __syncthreads();
        if (act) {
            #pragma unroll
            for (int r = 0; r < 4; ++r) {
                int row = r0 + r, s = row / 11, il = row - s * 11;
                float th = thrS[s];
                float t0 = 0.f, t1 = 0.f, t2 = 0.f, t3 = 0.f, cnt = 0.f;
                #pragma unroll
                for (int j = 0; j < 11; ++j) {
                    float4 vj = *(const float4*)&bufB[(s * 11 + j) * 68 + c0];
                    if (st == 0) {
                        t0 += fmaxf(uu[r][0] + vj.x, 0.f);
                        t1 += fmaxf(uu[r][1] + vj.y, 0.f);
                        t2 += fmaxf(uu[r][2] + vj.z, 0.f);
                        t3 += fmaxf(uu[r][3] + vj.w, 0.f);
                    } else {
                        float adj = (dcS[s * 121 + il * 11 + j] >= th) ? 1.f : 0.f;
                        t0 += adj * fmaxf(uu[r][0] + vj.x, 0.f);
                        t1 += adj * fmaxf(uu[r][1] + vj.y, 0.f);
                        t2 += adj * fmaxf(uu[r][2] + vj.z, 0.f);
                        t3 += adj * fmaxf(uu[r][3] + vj.w, 0.f);
                        cnt += adj;
                    }
                }
                float inv = (st == 0) ? (1.f / 11.f) : (1.f / (cnt + 1e-6f));
                a1v[r][0] = t0 * inv; a1v[r][1] = t1 * inv;
                a1v[r][2] = t2 * inv; a1v[r][3] = t3 * inv;
            }
        }
        __syncthreads();
        if (act) {
            float* dst = st ? bufB : bufA;
            #pragma unroll
            for (int r = 0; r < 4; ++r)
                *(float4*)&dst[(r0 + r) * 68 + c0] =
                    make_float4(a1v[r][0], a1v[r][1], a1v[r][2], a1v[r][3]);
        }
        __syncthreads();
    }

    // ---- inter = agg1 @ Wn1 -> out[:,256:512] ----
    {
        float ac2[4][16];
        #pragma unroll
        for (int r = 0; r < 4; ++r)
            #pragma unroll
            for (int c = 0; c < 16; ++c) ac2[r][c] = 0.f;
        for (int kh = 0; kh < 8; ++kh) {
            pfStore();
            if (kh < 7) pfLoad((const float4*)(Wn1) + (kh + 1) * 512,
                               (const float4*)(Wn1) + (kh + 1) * 512 + 256);
            else        pfLoad((const float4*)(ws + WN2L_O), (const float4*)(ws + WN2L_O) + 256);
            __syncthreads();
            if (act) {
                #pragma unroll
                for (int kq = 0; kq < 2; ++kq) {
                    float av[4][4];
                    #pragma unroll
                    for (int r = 0; r < 4; ++r) {
                        float4 a4 = *(const float4*)&bufA[(r0 + r) * 68 + kh * 8 + kq * 4];
                        av[r][0] = a4.x; av[r][1] = a4.y; av[r][2] = a4.z; av[r][3] = a4.w;
                    }
                    #pragma unroll
                    for (int kk = 0; kk < 4; ++kk) {
                        float4 b[4];
                        #pragma unroll
                        for (int j = 0; j < 4; ++j)
                            b[j] = *(const float4*)&Bs[(kq * 4 + kk) * 256 + c0 + j * 64];
                        #pragma unroll
                        for (int r = 0; r < 4; ++r) {
                            float a = av[r][kk];
                            #pragma unroll
                            for (int j = 0; j < 4; ++j) {
                                ac2[r][j * 4 + 0] += a * b[j].x;
                                ac2[r][j * 4 + 1] += a * b[j].y;
                                ac2[r][j * 4 + 2] += a * b[j].z;
                                ac2[r][j * 4 + 3] += a * b[j].w;
                            }
                        }
                    }
                }
            }
            __syncthreads();
        }
        if (act) {
            #pragma unroll
            for (int r = 0; r < 4; ++r) {
                size_t ob = (size_t)(rowBlk + r0 + r) * 576 + 256;
                #pragma unroll
                for (int j = 0; j < 4; ++j)
                    *(float4*)&out[ob + c0 + j * 64] =
                        make_float4(ac2[r][j * 4 + 0], ac2[r][j * 4 + 1],
                                    ac2[r][j * 4 + 2], ac2[r][j * 4 + 3]);
            }
        }
    }

    // ---- feat = agg2 @ Wn2L -> out[:,512:576] ----
    {
        float fa[4][4];
        #pragma unroll
        for (int r = 0; r < 4; ++r)
            #pragma unroll
            for (int c = 0; c < 4; ++c) fa[r][c] = 0.f;
        for (int kh = 0; kh < 2; ++kh) {
            pfStore();
            if (kh == 0) pfLoad((const float4*)(ws + WN2L_O) + 512,
                                (const float4*)(ws + WN2L_O) + 768);
            __syncthreads();
            if (act) {
                #pragma unroll
                for (int kq = 0; kq < 8; ++kq) {
                    float av[4][4];
                    #pragma unroll
                    for (int r = 0; r < 4; ++r) {
                        float4 a4 = *(const float4*)&bufB[(r0 + r) * 68 + kh * 32 + kq * 4];
                        av[r][0] = a4.x; av[r][1] = a4.y; av[r][2] = a4.z; av[r][3] = a4.w;
                    }
                    #pragma unroll
                    for (int kk = 0; kk < 4; ++kk) {
                        float4 b = *(const float4*)&Bs[(kq * 4 + kk) * 64 + c0];
                        #pragma unroll
                        for (int r = 0; r < 4; ++r) {
                            float a = av[r][kk];
                            fa[r][0] += a * b.x; fa[r][1] += a * b.y;
                            fa[r][2] += a * b.z; fa[r][3] += a * b.w;
                        }
                    }
                }
            }
            __syncthreads();
        }
        if (act) {
            #pragma unroll
            for (int r = 0; r < 4; ++r)
                *(float4*)&out[(size_t)(rowBlk + r0 + r) * 576 + 512 + c0] =
                    make_float4(fa[r][0], fa[r][1], fa[r][2], fa[r][3]);
        }
    }
}

extern "C" void kernel_launch(void* const* d_in, const int* in_sizes, int n_in,
                              void* d_out, int out_size, void* d_ws, size_t ws_size,
                              hipStream_t stream) {
    (void)in_sizes; (void)n_in; (void)out_size; (void)ws_size;
    const float* in     = (const float*)d_in[0];
    const float* W_in   = (const float*)d_in[1];
    const float* b_in   = (const float*)d_in[2];
    const float* W_pos  = (const float*)d_in[3];
    const float* b_pos  = (const float*)d_in[4];
    const float* W_fc2  = (const float*)d_in[5];
    const float* b_fc2  = (const float*)d_in[6];
    const float* W_fc3  = (const float*)d_in[7];
    const float* b_fc3  = (const float*)d_in[8];
    const float* Wh1    = (const float*)d_in[9];
    const float* We1    = (const float*)d_in[10];
    const float* Wn1    = (const float*)d_in[11];
    const float* Wh2    = (const float*)d_in[12];
    const float* We2    = (const float*)d_in[13];
    const float* Wn2    = (const float*)d_in[14];
    const float* W_line = (const float*)d_in[15];
    float* out = (float*)d_out;
    float* ws  = (float*)d_ws;

    k_preAB<<<224, TPB, 0, stream>>>(W_in, b_in, W_pos, b_pos, Wn2, W_line, ws);
    k_preC<<<264, TPB, 0, stream>>>(W_fc2, b_fc2, ws);
    k_preD<<<344, TPB, 0, stream>>>(W_fc3, b_fc3, ws);
    k_preE<<<172, TPB, 0, stream>>>(Wh1, Wh2, ws);
    k_main<<<1024, TPM, 0, stream>>>(in, We1, We2, Wn1, ws, out);
}

// Round 8
// 163.477 us; speedup vs baseline: 1.9165x; 1.0283x over previous
//
#include <hip/hip_runtime.h>

#define TPB 256
#define TPM 192   // k_main block size (3 waves)

// Problem dims
constexpr int B_ = 4096, A_ = 11;
constexpr int R_ = B_ * A_;       // 45056 rows

// ws offsets (floats)
constexpr int M_O     = 0;        // 8192   folded through fc2 (32x256)
constexpr int M2_O    = 8192;     // 8192   folded through fc3 (32x256)
constexpr int WC_O    = 16384;    // 1024   W_in @ W_pos_top
constexpr int XB_O    = 17408;    // 2048   per-timestep bias
constexpr int CB_O    = 19456;    // 256
constexpr int B2_O    = 19712;    // 2816   per-agent bias (11x256)
constexpr int WN2L_O  = 22528;    // 4096   Wn2 @ W_line (64x64)
constexpr int MH1_O   = 26624;    // 2048   M @ WfhA1 (32x64)
constexpr int BH1_O   = 28672;    // 704
constexpr int MH2_O   = 29376;    // 2048
constexpr int BH2_O   = 31424;    // 704
constexpr int WFA1_O  = 32768;    // 16384  Wfc3_top @ Wh1 (256x64)
constexpr int WFA2_O  = 49152;    // 16384  Wfc3_top @ Wh2
constexpr int BEYE1_O = 65536;    // 704    Wfc3_eye @ Wh1 (11x64)
constexpr int BEYE2_O = 66240;    // 704
constexpr int BB1_O   = 66944;    // 64     bfc3 @ Wh1
constexpr int BB2_O   = 67008;    // 64
constexpr int AG1_O   = 67584;    // agg1 (R_ x 64)
constexpr int SZ_RH   = R_ * 64;  // 2883584
constexpr int AG2_O   = AG1_O + SZ_RH;

// ================= pre kernels: wide split-K folds =================
// pattern: 256 threads = 32 outputs x 8 K-splits, LDS reduce.

__global__ __launch_bounds__(TPB) void k_preA(const float* __restrict__ Win,
                                              const float* __restrict__ bin,
                                              const float* __restrict__ Wpos,
                                              const float* __restrict__ bpos,
                                              const float* __restrict__ Wn2,
                                              const float* __restrict__ Wline,
                                              const float* __restrict__ Wfc3,
                                              const float* __restrict__ bfc3,
                                              const float* __restrict__ Wh1,
                                              const float* __restrict__ Wh2,
                                              float* __restrict__ ws) {
    __shared__ float red[8 * 33];
    const int t = threadIdx.x, o8 = t & 31, ks = t >> 5;
    const int bx = blockIdx.x;
    float p = 0.f;
    float base_add = 0.f;
    int out_idx = -1;
    if (bx < 64) {                       // xb[l][j], 2048 outs, K=512 (bin then pe inline)
        int o = bx * 32 + o8, l = o >> 8, j = o & 255;
        const float c0 = -logf(10000.f) / 256.f;
        for (int d = ks * 64; d < ks * 64 + 64; ++d) {
            float a;
            if (d < 256) a = bin[d];
            else {
                int dd = d - 256;
                float freq = expf((float)(dd & ~1) * c0);
                float ang = (float)l * freq;
                a = (dd & 1) ? cosf(ang) : sinf(ang);
            }
            p += a * Wpos[d * 256 + j];
        }
        out_idx = XB_O + o; base_add = bpos[j];
    } else if (bx < 192) {               // Wn2L, 4096 outs
        int o = (bx - 64) * 32 + o8, k = o >> 6, c = o & 63;
        #pragma unroll 8
        for (int d = ks * 32; d < ks * 32 + 32; ++d) p += Wn2[k * 256 + d] * Wline[d * 64 + c];
        out_idx = WN2L_O + o;
    } else if (bx < 704) {               // WfhA1 = Wfc3_top @ Wh1, 16384 outs
        int o = (bx - 192) * 32 + o8, e = o >> 6, c = o & 63;
        #pragma unroll 8
        for (int d = ks * 32; d < ks * 32 + 32; ++d) p += Wfc3[e * 256 + d] * Wh1[d * 64 + c];
        out_idx = WFA1_O + o;
    } else if (bx < 1216) {              // WfhA2 = Wfc3_top @ Wh2
        int o = (bx - 704) * 32 + o8, e = o >> 6, c = o & 63;
        #pragma unroll 8
        for (int d = ks * 32; d < ks * 32 + 32; ++d) p += Wfc3[e * 256 + d] * Wh2[d * 64 + c];
        out_idx = WFA2_O + o;
    } else if (bx < 1238) {              // bEye1 = Wfc3_eye @ Wh1, 704 outs
        int o = (bx - 1216) * 32 + o8, a = o >> 6, c = o & 63;
        #pragma unroll 8
        for (int d = ks * 32; d < ks * 32 + 32; ++d) p += Wfc3[(256 + a) * 256 + d] * Wh1[d * 64 + c];
        out_idx = BEYE1_O + o;
    } else if (bx < 1260) {              // bEye2
        int o = (bx - 1238) * 32 + o8, a = o >> 6, c = o & 63;
        #pragma unroll 8
        for (int d = ks * 32; d < ks * 32 + 32; ++d) p += Wfc3[(256 + a) * 256 + d] * Wh2[d * 64 + c];
        out_idx = BEYE2_O + o;
    } else if (bx < 1262) {              // bb1 = bfc3 @ Wh1, 64 outs
        int c = (bx - 1260) * 32 + o8;
        #pragma unroll 8
        for (int d = ks * 32; d < ks * 32 + 32; ++d) p += bfc3[d] * Wh1[d * 64 + c];
        out_idx = BB1_O + c;
    } else if (bx < 1264) {              // bb2
        int c = (bx - 1262) * 32 + o8;
        #pragma unroll 8
        for (int d = ks * 32; d < ks * 32 + 32; ++d) p += bfc3[d] * Wh2[d * 64 + c];
        out_idx = BB2_O + c;
    } else {                             // Wc = Win @ Wpos_top, 1024 outs
        int o = (bx - 1264) * 32 + o8, i = o >> 8, j = o & 255;
        #pragma unroll 8
        for (int d = ks * 32; d < ks * 32 + 32; ++d) p += Win[i * 256 + d] * Wpos[d * 256 + j];
        out_idx = WC_O + o;
    }
    red[ks * 33 + o8] = p;
    // stash per-block base add for lane t<32 via LDS round (base depends on out lane only)
    __shared__ float baseS[32];
    if (ks == 0) baseS[o8] = base_add;
    __syncthreads();
    if (t < 32) {
        float s = baseS[t];
        #pragma unroll
        for (int m = 0; m < 8; ++m) s += red[m * 33 + t];
        ws[out_idx - o8 + t] = s;
    }
}

__global__ __launch_bounds__(TPB) void k_preC(const float* __restrict__ Wfc2,
                                              const float* __restrict__ bfc2,
                                              float* __restrict__ ws) {
    __shared__ float red[8 * 33];
    const int t = threadIdx.x, o8 = t & 31, ks = t >> 5;
    const int bx = blockIdx.x;
    if (bx < 256) {                      // M[k][j], 8192 outs, K=256; k=(l,i)
        int o = bx * 32 + o8, k = o >> 8, j = o & 255;
        int l = k >> 2, i = k & 3;
        const float* Ar = ws + WC_O + i * 256;
        const float* Br = Wfc2 + l * 65536 + j;
        float p = 0.f;
        #pragma unroll 8
        for (int d = ks * 32; d < ks * 32 + 32; ++d) p += Ar[d] * Br[d * 256];
        red[ks * 33 + o8] = p;
        __syncthreads();
        if (t < 32) {
            float s = 0.f;
            #pragma unroll
            for (int m = 0; m < 8; ++m) s += red[m * 33 + t];
            ws[M_O + bx * 32 + t] = s;
        }
    } else {                             // cb[j], 256 outs, K=2048
        int j = (bx - 256) * 32 + o8;
        const float* Ar = ws + XB_O;
        float p = 0.f;
        #pragma unroll 4
        for (int dk = ks * 256; dk < ks * 256 + 256; ++dk) p += Ar[dk] * Wfc2[dk * 256 + j];
        red[ks * 33 + o8] = p;
        __syncthreads();
        if (t < 32) {
            int jj = (bx - 256) * 32 + t;
            float s = bfc2[jj];
            #pragma unroll
            for (int m = 0; m < 8; ++m) s += red[m * 33 + t];
            ws[CB_O + jj] = s;
        }
    }
}

__global__ __launch_bounds__(TPB) void k_preD(const float* __restrict__ Wfc3,
                                              const float* __restrict__ bfc3,
                                              float* __restrict__ ws) {
    __shared__ float red[8 * 33];
    const int t = threadIdx.x, o8 = t & 31, ks = t >> 5;
    const int bx = blockIdx.x;
    float p = 0.f;
    int out_base = -1;
    float fin = 0.f;
    int oo32 = 0;
    if (bx < 256) {                      // M2 = M @ Wfc3_top, 8192 outs
        int o = bx * 32 + o8, k = o >> 8, j = o & 255;
        const float* Ar = ws + M_O + k * 256;
        #pragma unroll 8
        for (int d = ks * 32; d < ks * 32 + 32; ++d) p += Ar[d] * Wfc3[d * 256 + j];
        out_base = M2_O; oo32 = bx * 32;
    } else if (bx < 344) {               // bias2[a][j], 2816 outs
        int o = (bx - 256) * 32 + o8, j = o & 255;
        const float* Ar = ws + CB_O;
        #pragma unroll 8
        for (int d = ks * 32; d < ks * 32 + 32; ++d) p += Ar[d] * Wfc3[d * 256 + j];
        out_base = B2_O; oo32 = (bx - 256) * 32;
    } else if (bx < 408) {               // Mh1 = M @ WfhA1, 2048 outs
        int o = (bx - 344) * 32 + o8, k = o >> 6, c = o & 63;
        const float* Ar = ws + M_O + k * 256;
        const float* Br = ws + WFA1_O;
        #pragma unroll 8
        for (int d = ks * 32; d < ks * 32 + 32; ++d) p += Ar[d] * Br[d * 64 + c];
        out_base = MH1_O; oo32 = (bx - 344) * 32;
    } else if (bx < 472) {               // Mh2 = M @ WfhA2
        int o = (bx - 408) * 32 + o8, k = o >> 6, c = o & 63;
        const float* Ar = ws + M_O + k * 256;
        const float* Br = ws + WFA2_O;
        #pragma unroll 8
        for (int d = ks * 32; d < ks * 32 + 32; ++d) p += Ar[d] * Br[d * 64 + c];
        out_base = MH2_O; oo32 = (bx - 408) * 32;
    } else if (bx < 494) {               // bh1 = cb@WfhA1 + bEye1 + bb1, 704 outs
        int o = (bx - 472) * 32 + o8, c = o & 63;
        const float* Ar = ws + CB_O;
        const float* Br = ws + WFA1_O;
        #pragma unroll 8
        for (int d = ks * 32; d < ks * 32 + 32; ++d) p += Ar[d] * Br[d * 64 + c];
        out_base = BH1_O; oo32 = (bx - 472) * 32;
    } else {                             // bh2
        int o = (bx - 494) * 32 + o8, c = o & 63;
        const float* Ar = ws + CB_O;
        const float* Br = ws + WFA2_O;
        #pragma unroll 8
        for (int d = ks * 32; d < ks * 32 + 32; ++d) p += Ar[d] * Br[d * 64 + c];
        out_base = BH2_O; oo32 = (bx - 494) * 32;
    }
    red[ks * 33 + o8] = p;
    __syncthreads();
    if (t < 32) {
        int oo = oo32 + t;
        float s;
        if (out_base == B2_O) {
            int aa = oo >> 8, jj = oo & 255;
            s = bfc3[jj] + Wfc3[(256 + aa) * 256 + jj];
        } else if (out_base == BH1_O) {
            int aa = oo >> 6, cc = oo & 63;
            s = ws[BB1_O + cc] + ws[BEYE1_O + aa * 64 + cc];
        } else if (out_base == BH2_O) {
            int aa = oo >> 6, cc = oo & 63;
            s = ws[BB2_O + cc] + ws[BEYE2_O + aa * 64 + cc];
        } else s = 0.f;
        #pragma unroll
        for (int m = 0; m < 8; ++m) s += red[m * 33 + t];
        ws[out_base + oo] = s;
    }
    (void)fin;
}

// ================= k_main: ftraj + dots/corr + NMP, agg -> ws =================

__global__ __launch_bounds__(TPM) void k_main(const float* __restrict__ in,
                                              const float* __restrict__ We1g,
                                              const float* __restrict__ We2g,
                                              float* ws,
                                              float* out) {
    __shared__ float inS[44 * 36];     // 6336 B
    __shared__ float buf[44 * 68];     // 11968 B: ft-slices / h / v
    __shared__ float Bs[2048];         // 8192 B
    __shared__ float dcS[484];
    __shared__ float thrS[4];
    const int t = threadIdx.x;
    const int rg = t >> 4, cg = t & 15;
    const int r0 = rg * 4, c0 = cg * 4;
    const int rowBlk = blockIdx.x * 44;
    const bool act = rg < 11;

    float4 pf0, pf1, pf2;
    auto pfLoad = [&](const float4* lo, const float4* hi) {
        pf0 = lo[t];
        pf1 = (t < 64) ? lo[t + 192] : hi[t - 64];
        if (t < 128) pf2 = hi[t + 128];
    };
    auto pfStore = [&]() {
        float4* d = (float4*)Bs;
        d[t] = pf0; d[t + 192] = pf1;
        if (t < 128) d[t + 384] = pf2;
    };

    pfLoad((const float4*)(ws + M2_O), (const float4*)(ws + M2_O) + 256);
    for (int o = t; o < 352; o += TPM) {
        int row = o >> 3, c4 = o & 7;
        *(float4*)&inS[row * 36 + c4 * 4] =
            *(const float4*)&in[(size_t)(rowBlk + row) * 32 + c4 * 4];
    }
    __syncthreads();

    // ---- ftraj = in @ M2 + bias2 ----
    float acc[4][16];
    #pragma unroll
    for (int r = 0; r < 4; ++r)
        #pragma unroll
        for (int c = 0; c < 16; ++c) acc[r][c] = 0.f;
    for (int kh = 0; kh < 4; ++kh) {
        pfStore();
        if (kh < 3) pfLoad((const float4*)(ws + M2_O) + (kh + 1) * 512,
                           (const float4*)(ws + M2_O) + (kh + 1) * 512 + 256);
        else        pfLoad((const float4*)(ws + MH1_O), (const float4*)(ws + MH1_O) + 256);
        __syncthreads();
        if (act) {
            #pragma unroll
            for (int kq = 0; kq < 2; ++kq) {
                float av[4][4];
                #pragma unroll
                for (int r = 0; r < 4; ++r) {
                    float4 a4 = *(const float4*)&inS[(r0 + r) * 36 + kh * 8 + kq * 4];
                    av[r][0] = a4.x; av[r][1] = a4.y; av[r][2] = a4.z; av[r][3] = a4.w;
                }
                #pragma unroll
                for (int kk = 0; kk < 4; ++kk) {
                    float4 b[4];
                    #pragma unroll
                    for (int j = 0; j < 4; ++j)
                        b[j] = *(const float4*)&Bs[(kq * 4 + kk) * 256 + c0 + j * 64];
                    #pragma unroll
                    for (int r = 0; r < 4; ++r) {
                        float a = av[r][kk];
                        #pragma unroll
                        for (int j = 0; j < 4; ++j) {
                            acc[r][j * 4 + 0] += a * b[j].x;
                            acc[r][j * 4 + 1] += a * b[j].y;
                            acc[r][j * 4 + 2] += a * b[j].z;
                            acc[r][j * 4 + 3] += a * b[j].w;
                        }
                    }
                }
            }
        }
        __syncthreads();
    }
    if (act) {
        #pragma unroll
        for (int r = 0; r < 4; ++r) {
            int row = r0 + r, il = row % 11;
            size_t ob = (size_t)(rowBlk + row) * 576;
            #pragma unroll
            for (int j = 0; j < 4; ++j) {
                float4 b2 = *(const float4*)&ws[B2_O + il * 256 + c0 + j * 64];
                acc[r][j * 4 + 0] += b2.x; acc[r][j * 4 + 1] += b2.y;
                acc[r][j * 4 + 2] += b2.z; acc[r][j * 4 + 3] += b2.w;
                *(float4*)&out[ob + c0 + j * 64] =
                    make_float4(acc[r][j * 4 + 0], acc[r][j * 4 + 1],
                                acc[r][j * 4 + 2], acc[r][j * 4 + 3]);
            }
        }
    }

    // ---- dots via 4 LDS slices ----
    bool has0 = false, has1 = false;
    int s0_ = 0, i0_ = 0, j0_ = 0, s1_ = 0, i1_ = 0, j1_ = 0;
    {
        int idx = t;
        if (idx < 264) {
            has0 = true; s0_ = idx / 66; int p = idx % 66; int i = 0;
            while (p >= 11 - i) { p -= 11 - i; ++i; }
            i0_ = i; j0_ = i + p;
        }
        idx = t + TPM;
        if (idx < 264) {
            has1 = true; s1_ = idx / 66; int p = idx % 66; int i = 0;
            while (p >= 11 - i) { p -= 11 - i; ++i; }
            i1_ = i; j1_ = i + p;
        }
    }
    float dacc0 = 0.f, dacc1 = 0.f;
    for (int sl = 0; sl < 4; ++sl) {
        if (act) {
            #pragma unroll
            for (int r = 0; r < 4; ++r)
                *(float4*)&buf[(r0 + r) * 68 + c0] =
                    make_float4(acc[r][sl * 4 + 0], acc[r][sl * 4 + 1],
                                acc[r][sl * 4 + 2], acc[r][sl * 4 + 3]);
        }
        __syncthreads();
        if (has0) {
            const float* ra = &buf[(s0_ * 11 + i0_) * 68];
            const float* rb = &buf[(s0_ * 11 + j0_) * 68];
            #pragma unroll
            for (int c = 0; c < 16; ++c) {
                float4 a = *(const float4*)&ra[c * 4];
                float4 b = *(const float4*)&rb[c * 4];
                dacc0 += a.x * b.x + a.y * b.y + a.z * b.z + a.w * b.w;
            }
        }
        if (has1) {
            const float* ra = &buf[(s1_ * 11 + i1_) * 68];
            const float* rb = &buf[(s1_ * 11 + j1_) * 68];
            #pragma unroll
            for (int c = 0; c < 16; ++c) {
                float4 a = *(const float4*)&ra[c * 4];
                float4 b = *(const float4*)&rb[c * 4];
                dacc1 += a.x * b.x + a.y * b.y + a.z * b.z + a.w * b.w;
            }
        }
        __syncthreads();
    }
    if (has0) { dcS[s0_ * 121 + i0_ * 11 + j0_] = dacc0;
                dcS[s0_ * 121 + j0_ * 11 + i0_] = dacc0; }
    if (has1) { dcS[s1_ * 121 + i1_ * 11 + j1_] = dacc1;
                dcS[s1_ * 121 + j1_ * 11 + i1_] = dacc1; }
    __syncthreads();

    // ---- corr + per-scene threshold ----
    {
        float cc0, cc1, cc2 = 0.f;
        {
            int idx = t; int si = idx / 121, p = idx % 121, i = p / 11, j = p % 11;
            cc0 = dcS[idx] * rsqrtf(dcS[si * 121 + i * 12] * dcS[si * 121 + j * 12]);
        }
        {
            int idx = t + TPM; int si = idx / 121, p = idx % 121, i = p / 11, j = p % 11;
            cc1 = dcS[idx] * rsqrtf(dcS[si * 121 + i * 12] * dcS[si * 121 + j * 12]);
        }
        if (t + 2 * TPM < 484) {
            int idx = t + 2 * TPM; int si = idx / 121, p = idx % 121, i = p / 11, j = p % 11;
            cc2 = dcS[idx] * rsqrtf(dcS[si * 121 + i * 12] * dcS[si * 121 + j * 12]);
        }
        __syncthreads();
        dcS[t] = cc0;
        dcS[t + TPM] = cc1;
        if (t + 2 * TPM < 484) dcS[t + 2 * TPM] = cc2;
    }
    __syncthreads();
    if (t < 4) {
        float mn = 3.0e38f;
        for (int p = 0; p < 121; ++p) mn = fminf(mn, dcS[t * 121 + p]);
        thrS[t] = (mn < 0.4f) ? 0.4f : ((mn > 0.4f && mn < 0.6f) ? mn + 0.1f : mn + 0.03f);
    }
    __syncthreads();

    // ---- two NMP stages; agg straight to ws ----
    for (int st = 0; st < 2; ++st) {
        const float* bh = ws + (st ? BH2_O : BH1_O);
        const float* We = st ? We2g : We1g;
        pfStore();                                   // Mh
        pfLoad((const float4*)(We), (const float4*)(We + 4096));
        __syncthreads();
        float hh[4][4];
        #pragma unroll
        for (int r = 0; r < 4; ++r)
            #pragma unroll
            for (int c = 0; c < 4; ++c) hh[r][c] = 0.f;
        if (act) {
            #pragma unroll
            for (int kq = 0; kq < 8; ++kq) {
                float av[4][4];
                #pragma unroll
                for (int r = 0; r < 4; ++r) {
                    float4 a4 = *(const float4*)&inS[(r0 + r) * 36 + kq * 4];
                    av[r][0] = a4.x; av[r][1] = a4.y; av[r][2] = a4.z; av[r][3] = a4.w;
                }
                #pragma unroll
                for (int kk = 0; kk < 4; ++kk) {
                    float4 b = *(const float4*)&Bs[(kq * 4 + kk) * 64 + c0];
                    #pragma unroll
                    for (int r = 0; r < 4; ++r) {
                        float a = av[r][kk];
                        hh[r][0] += a * b.x; hh[r][1] += a * b.y;
                        hh[r][2] += a * b.z; hh[r][3] += a * b.w;
                    }
                }
            }
            #pragma unroll
            for (int r = 0; r < 4; ++r) {
                int il = (r0 + r) % 11;
                float4 b = *(const float4*)&bh[il * 64 + c0];
                *(float4*)&buf[(r0 + r) * 68 + c0] =
                    make_float4(fmaxf(hh[r][0] + b.x, 0.f), fmaxf(hh[r][1] + b.y, 0.f),
                                fmaxf(hh[r][2] + b.z, 0.f), fmaxf(hh[r][3] + b.w, 0.f));
            }
        }
        __syncthreads();
        float uu[4][4], vv[4][4];
        #pragma unroll
        for (int r = 0; r < 4; ++r)
            #pragma unroll
            for (int c = 0; c < 4; ++c) { uu[r][c] = 0.f; vv[r][c] = 0.f; }
        for (int kh = 0; kh < 4; ++kh) {
            pfStore();
            if (kh < 3)
                pfLoad((const float4*)(We + (kh + 1) * 1024),
                       (const float4*)(We + 4096 + (kh + 1) * 1024));
            else if (st == 0)
                pfLoad((const float4*)(ws + MH2_O), (const float4*)(ws + MH2_O) + 256);
            __syncthreads();
            if (act) {
                #pragma unroll
                for (int kq = 0; kq < 4; ++kq) {
                    float av[4][4];
                    #pragma unroll
                    for (int r = 0; r < 4; ++r) {
                        float4 a4 = *(const float4*)&buf[(r0 + r) * 68 + kh * 16 + kq * 4];
                        av[r][0] = a4.x; av[r][1] = a4.y; av[r][2] = a4.z; av[r][3] = a4.w;
                    }
                    #pragma unroll
                    for (int kk = 0; kk < 4; ++kk) {
                        float4 bu = *(const float4*)&Bs[(kq * 4 + kk) * 64 + c0];
                        float4 bv = *(const float4*)&Bs[1024 + (kq * 4 + kk) * 64 + c0];
                        #pragma unroll
                        for (int r = 0; r < 4; ++r) {
                            float a = av[r][kk];
                            uu[r][0] += a * bu.x; uu[r][1] += a * bu.y;
                            uu[r][2] += a * bu.z; uu[r][3] += a * bu.w;
                            vv[r][0] += a * bv.x; vv[r][1] += a * bv.y;
                            vv[r][2] += a * bv.z; vv[r][3] += a * bv.w;
                        }
                    }
                }
            }
            __syncthreads();
        }
        if (act) {   // v over h (h dead)
            #pragma unroll
            for (int r = 0; r < 4; ++r)
                *(float4*)&buf[(r0 + r) * 68 + c0] =
                    make_float4(vv[r][0], vv[r][1], vv[r][2], vv[r][3]);
        }
        __syncthreads();
        if (act) {
            float* ag = ws + (st ? AG2_O : AG1_O);
            #pragma unroll
            for (int r = 0; r < 4; ++r) {
                int row = r0 + r, s = row / 11, il = row - s * 11;
                float th = thrS[s];
                float t0 = 0.f, t1 = 0.f, t2 = 0.f, t3 = 0.f, cnt = 0.f;
                #pragma unroll
                for (int j = 0; j < 11; ++j) {
                    float4 vj = *(const float4*)&buf[(s * 11 + j) * 68 + c0];
                    if (st == 0) {
                        t0 += fmaxf(uu[r][0] + vj.x, 0.f);
                        t1 += fmaxf(uu[r][1] + vj.y, 0.f);
                        t2 += fmaxf(uu[r][2] + vj.z, 0.f);
                        t3 += fmaxf(uu[r][3] + vj.w, 0.f);
                    } else {
                        float adj = (dcS[s * 121 + il * 11 + j] >= th) ? 1.f : 0.f;
                        t0 += adj * fmaxf(uu[r][0] + vj.x, 0.f);
                        t1 += adj * fmaxf(uu[r][1] + vj.y, 0.f);
                        t2 += adj * fmaxf(uu[r][2] + vj.z, 0.f);
                        t3 += adj * fmaxf(uu[r][3] + vj.w, 0.f);
                        cnt += adj;
                    }
                }
                float inv = (st == 0) ? (1.f / 11.f) : (1.f / (cnt + 1e-6f));
                *(float4*)&ag[(size_t)(rowBlk + row) * 64 + c0] =
                    make_float4(t0 * inv, t1 * inv, t2 * inv, t3 * inv);
            }
        }
        __syncthreads();   // buf reads done before next stage's h-write
    }
}

// ================= k_tail: inter = agg1@Wn1, feat = agg2@Wn2L =================

__global__ __launch_bounds__(TPB) void k_tail(const float* __restrict__ Wn1,
                                              const float* __restrict__ ws,
                                              float* __restrict__ out) {
    __shared__ float aS[64 * 68];    // 17.4 KB
    __shared__ float Bs[2048];       // 8 KB
    const int t = threadIdx.x;
    const int rowBase = blockIdx.x * 64;
    const int tg = t >> 4, tc = t & 15;
    const int r0 = tg * 4, c0 = tc * 4;

    {   // stage agg1
        const float4* s1 = (const float4*)(ws + AG1_O + (size_t)rowBase * 64);
        #pragma unroll
        for (int o = t; o < 1024; o += TPB) {
            int row = o >> 4, c4 = o & 15;
            *(float4*)&aS[row * 68 + c4 * 4] = s1[o];
        }
    }
    __syncthreads();

    // ---- inter = agg1 @ Wn1 (K=64) ----
    {
        float acc[4][16];
        #pragma unroll
        for (int r = 0; r < 4; ++r)
            #pragma unroll
            for (int c = 0; c < 16; ++c) acc[r][c] = 0.f;
        for (int kh = 0; kh < 8; ++kh) {
            if (kh) __syncthreads();
            {
                const float4* src = (const float4*)(Wn1 + kh * 2048);
                float4* dst = (float4*)Bs;
                dst[t] = src[t];
                dst[t + 256] = src[t + 256];
            }
            __syncthreads();
            #pragma unroll
            for (int kq = 0; kq < 2; ++kq) {
                float av[4][4];
                #pragma unroll
                for (int r = 0; r < 4; ++r) {
                    float4 a4 = *(const float4*)&aS[(r0 + r) * 68 + kh * 8 + kq * 4];
                    av[r][0] = a4.x; av[r][1] = a4.y; av[r][2] = a4.z; av[r][3] = a4.w;
                }
                #pragma unroll
                for (int kk = 0; kk < 4; ++kk) {
                    float4 b[4];
                    #pragma unroll
                    for (int j = 0; j < 4; ++j)
                        b[j] = *(const float4*)&Bs[(kq * 4 + kk) * 256 + c0 + j * 64];
                    #pragma unroll
                    for (int r = 0; r < 4; ++r) {
                        float a = av[r][kk];
                        #pragma unroll
                        for (int j = 0; j < 4; ++j) {
                            acc[r][j * 4 + 0] += a * b[j].x;
                            acc[r][j * 4 + 1] += a * b[j].y;
                            acc[r][j * 4 + 2] += a * b[j].z;
                            acc[r][j * 4 + 3] += a * b[j].w;
                        }
                    }
                }
            }
        }
        #pragma unroll
        for (int r = 0; r < 4; ++r) {
            size_t ob = (size_t)(rowBase + r0 + r) * 576 + 256;
            #pragma unroll
            for (int j = 0; j < 4; ++j)
                *(float4*)&out[ob + c0 + j * 64] =
                    make_float4(acc[r][j * 4 + 0], acc[r][j * 4 + 1],
                                acc[r][j * 4 + 2], acc[r][j * 4 + 3]);
        }
    }

    __syncthreads();
    {   // restage aS with agg2
        const float4* s2 = (const float4*)(ws + AG2_O + (size_t)rowBase * 64);
        #pragma unroll
        for (int o = t; o < 1024; o += TPB) {
            int row = o >> 4, c4 = o & 15;
            *(float4*)&aS[row * 68 + c4 * 4] = s2[o];
        }
    }
    // ---- feat = agg2 @ Wn2L (K=64) ----
    {
        float fa[4][4];
        #pragma unroll
        for (int r = 0; r < 4; ++r)
            #pragma unroll
            for (int c = 0; c < 4; ++c) fa[r][c] = 0.f;
        for (int kh = 0; kh < 2; ++kh) {
            __syncthreads();
            {
                const float4* src = (const float4*)(ws + WN2L_O + kh * 2048);
                float4* dst = (float4*)Bs;
                dst[t] = src[t];
                dst[t + 256] = src[t + 256];
            }
            __syncthreads();
            #pragma unroll
            for (int kq = 0; kq < 8; ++kq) {
                float av[4][4];
                #pragma unroll
                for (int r = 0; r < 4; ++r) {
                    float4 a4 = *(const float4*)&aS[(r0 + r) * 68 + kh * 32 + kq * 4];
                    av[r][0] = a4.x; av[r][1] = a4.y; av[r][2] = a4.z; av[r][3] = a4.w;
                }
                #pragma unroll
                for (int kk = 0; kk < 4; ++kk) {
                    float4 b = *(const float4*)&Bs[(kq * 4 + kk) * 64 + c0];
                    #pragma unroll
                    for (int r = 0; r < 4; ++r) {
                        float a = av[r][kk];
                        fa[r][0] += a * b.x; fa[r][1] += a * b.y;
                        fa[r][2] += a * b.z; fa[r][3] += a * b.w;
                    }
                }
            }
        }
        #pragma unroll
        for (int r = 0; r < 4; ++r)
            *(float4*)&out[(size_t)(rowBase + r0 + r) * 576 + 512 + c0] =
                make_float4(fa[r][0], fa[r][1], fa[r][2], fa[r][3]);
    }
}

extern "C" void kernel_launch(void* const* d_in, const int* in_sizes, int n_in,
                              void* d_out, int out_size, void* d_ws, size_t ws_size,
                              hipStream_t stream) {
    (void)in_sizes; (void)n_in; (void)out_size; (void)ws_size;
    const float* in     = (const float*)d_in[0];
    const float* W_in   = (const float*)d_in[1];
    const float* b_in   = (const float*)d_in[2];
    const float* W_pos  = (const float*)d_in[3];
    const float* b_pos  = (const float*)d_in[4];
    const float* W_fc2  = (const float*)d_in[5];
    const float* b_fc2  = (const float*)d_in[6];
    const float* W_fc3  = (const float*)d_in[7];
    const float* b_fc3  = (const float*)d_in[8];
    const float* Wh1    = (const float*)d_in[9];
    const float* We1    = (const float*)d_in[10];
    const float* Wn1    = (const float*)d_in[11];
    const float* Wh2    = (const float*)d_in[12];
    const float* We2    = (const float*)d_in[13];
    const float* Wn2    = (const float*)d_in[14];
    const float* W_line = (const float*)d_in[15];
    float* out = (float*)d_out;
    float* ws  = (float*)d_ws;

    k_preA<<<1296, TPB, 0, stream>>>(W_in, b_in, W_pos, b_pos, Wn2, W_line,
                                     W_fc3, b_fc3, Wh1, Wh2, ws);
    k_preC<<<264, TPB, 0, stream>>>(W_fc2, b_fc2, ws);
    k_preD<<<516, TPB, 0, stream>>>(W_fc3, b_fc3, ws);
    k_main<<<1024, TPM, 0, stream>>>(in, We1, We2, ws, out);
    k_tail<<<R_ / 64, TPB, 0, stream>>>(Wn1, ws, out);
}